// Round 2
// baseline (578.983 us; speedup 1.0000x reference)
//
#include <hip/hip_runtime.h>
#include <cstdint>

typedef __bf16 bf16x8 __attribute__((ext_vector_type(8)));
typedef float f32x4 __attribute__((ext_vector_type(4)));
typedef float f32x16 __attribute__((ext_vector_type(16)));
typedef unsigned int u32x4 __attribute__((ext_vector_type(4)));
typedef unsigned int u32x2 __attribute__((ext_vector_type(2)));
typedef unsigned short u16;
typedef unsigned int u32;

// Problem constants (fixed by reference)
#define HH 128
#define WW 128
#define CC 64
#define QQ 65536
#define BB 4

// LDS activation row stride in u16: 256 features + 8 pad.
// 264 u16 = 132 words; 132 mod 32 = 4 -> rows rotate bank-groups by 4.
// 32-row b128 reads (32x32 B-frags) and b64 epilogue writes are both at the
// LDS phase minimum with this stride. All addresses stay ADDITIVE.
#define RS 264

// Packed-weight offsets in bf16 elements inside d_ws.
// 32x32x16 fragment = 64 lanes x 8 bf16 = 512 elems; frag (ks,nt) at
// (ks*8+nt)*512, nt fastest.  L0: 5 ks x 8 nt = 40; L1-3: 16 x 8 = 128 each.
// w4 keeps the 16x16x32 layout (N=3 pads to 16, not 32): 8 frags.
#define L0_OFF 0        // 40 * 512 = 20480
#define L1_OFF 20480    // 128 * 512 = 65536
#define L2_OFF 86016
#define L3_OFF 151552
#define W4_OFF 217088   // 8 * 512 = 4096 -> total 221184 elems = 442368 B
#define FEATT_BYTE_OFF 524288u  // featT: 4*128*128*64 bf16 = 8388608 B

// ---------------------------------------------------------------------------
// Pack w0..w3 into 32x32x16 MFMA fragment order (bf16):
//   frag (ks,nt): lane l, j=0..7 holds W[ks*16 + (l>>5)*8 + j][nt*32 + (l&31)]
// w4 (256->3) stays in 16x16x32 fragment order (kt-major, NT=1).
// ---------------------------------------------------------------------------
__global__ void pack_weights(const float* __restrict__ w0,
                             const float* __restrict__ w1,
                             const float* __restrict__ w2,
                             const float* __restrict__ w3,
                             const float* __restrict__ w4,
                             u16* __restrict__ ws_us) {
    int bid = blockIdx.x;
    int lane = threadIdx.x;  // 64
    int dst, kbase, n, Ksrc, Ncols;
    const float* w;
    if (bid < 424) {  // 32x32x16 fragments for L0..L3
        int tile, off;
        if (bid < 40)       { tile = bid;       off = L0_OFF; w = w0; Ksrc = 68;  }
        else if (bid < 168) { tile = bid - 40;  off = L1_OFF; w = w1; Ksrc = 256; }
        else if (bid < 296) { tile = bid - 168; off = L2_OFF; w = w2; Ksrc = 256; }
        else                { tile = bid - 296; off = L3_OFF; w = w3; Ksrc = 256; }
        int nt = tile & 7, ks = tile >> 3;
        n = nt * 32 + (lane & 31);
        kbase = ks * 16 + (lane >> 5) * 8;
        Ncols = 256;
        dst = off + tile * 512 + lane * 8;
    } else {          // w4: 16x16x32 fragments, frag kt = bid-424
        int kt = bid - 424;
        n = lane & 15;
        kbase = kt * 32 + (lane >> 4) * 8;
        w = w4; Ksrc = 256; Ncols = 3;
        dst = W4_OFF + kt * 512 + lane * 8;
    }
    unsigned int d[4];
    for (int i = 0; i < 4; ++i) {
        unsigned int lo, hi;
        {
            int k = kbase + 2 * i;
            float x = (k < Ksrc && n < Ncols) ? w[k * Ncols + n] : 0.0f;
            __bf16 hb = (__bf16)x;
            lo = (unsigned int)__builtin_bit_cast(u16, hb);
        }
        {
            int k = kbase + 2 * i + 1;
            float x = (k < Ksrc && n < Ncols) ? w[k * Ncols + n] : 0.0f;
            __bf16 hb = (__bf16)x;
            hi = (unsigned int)__builtin_bit_cast(u16, hb);
        }
        d[i] = lo | (hi << 16);
    }
    u32x4 pk = { d[0], d[1], d[2], d[3] };
    *reinterpret_cast<u32x4*>(ws_us + dst) = pk;
}

// ---------------------------------------------------------------------------
// feat [B,C,H,W] fp32 -> featT [B,H,W,C] bf16 (per-pixel gather = one
// contiguous 128B read). One block per (b, y) row; LDS transpose.
// ---------------------------------------------------------------------------
__global__ void prep_featT(const float* __restrict__ feat, u16* __restrict__ featT) {
    __shared__ u16 tile[128 * 66];
    int bid = blockIdx.x;
    int b = bid >> 7, y = bid & 127;
    for (int idx = threadIdx.x; idx < CC * WW; idx += 256) {
        int c = idx >> 7, x = idx & 127;
        float v = feat[(((b * CC + c) * HH + y) * WW) + x];
        __bf16 hb = (__bf16)v;
        tile[x * 66 + c] = __builtin_bit_cast(u16, hb);
    }
    __syncthreads();
    for (int idx = threadIdx.x; idx < 2048; idx += 256) {
        int x = idx >> 4, c4 = (idx & 15) * 4;
        const u16* src = tile + x * 66 + c4;
        u32x2 d;
        d[0] = (unsigned int)src[0] | ((unsigned int)src[1] << 16);
        d[1] = (unsigned int)src[2] | ((unsigned int)src[3] << 16);
        *reinterpret_cast<u32x2*>(featT + ((b * HH + y) * WW + x) * CC + c4) = d;
    }
}

// ---------------------------------------------------------------------------
// Preload the first THREE ksteps' fragments (6 x 16B) of a layer; issued
// BEFORE a barrier so L2 latency overlaps the barrier wait + epilogue.
// Strides in u32x4 units: kstr = 512 for 32x32 layers (ks stride), 128 for
// the w4 16x16 layout (kt pairs); frag pair within a kstep is +64.
// ---------------------------------------------------------------------------
__device__ __forceinline__ void preload6(u32x4 w[6], const u32x4* __restrict__ b,
                                         int v, int kstr) {
    w[0] = b[v];
    w[1] = b[v + 64];
    w[2] = b[v + kstr];
    w[3] = b[v + kstr + 64];
    w[4] = b[v + 2 * kstr];
    w[5] = b[v + 2 * kstr + 64];
}

// ---------------------------------------------------------------------------
// Transposed GEMM layer via 32x32x16 MFMA, PING-PONG: reads src, writes dst.
// No internal barrier: dst != src, so the epilogue can stream out while other
// waves are still reading src.  Caller places ONE barrier between layers.
// Weight frags: wq[3][2] ring (ks, ks+1, ks+2 in flight -> issue distance
// ~2.5 ksteps covers L2 latency).  X rows: xc[2][2] ring (ks, ks+1 in flight
// -> ~1.5 ksteps covers LDS latency).  All LDS addrs: one base + immediates.
// C layout (verified): sample col = lane&31, feature row =
// (reg&3) + 8*(reg>>2) + 4*(lane>>5).
// ---------------------------------------------------------------------------
template <int NKS>
__device__ __forceinline__ void gemm32(const u16* __restrict__ src,
                                       u16* __restrict__ dst,
                                       const u32x4* __restrict__ wbase,
                                       const float* __restrict__ bias,
                                       int wave, int lane,
                                       const u32x4 wpre[6],
                                       u32x4 wnxt[6],
                                       const u32x4* __restrict__ wnb,
                                       int vnxt, int nkstr) {
    f32x16 acc[2][2] = {};                        // [ft][st]
    const int l31 = lane & 31;
    const int hi = lane >> 5;
    const int voff = wave * 128 + lane;           // u32x4 index of frag(ks=0, nt=wave*2)
    const u16* xb = src + l31 * RS + hi * 8;      // one LDS base for ALL reads
    u16* db = dst + l31 * RS + wave * 64 + hi * 4;

    u32x4 wq[3][2];
    wq[0][0] = wpre[0]; wq[0][1] = wpre[1];
    wq[1][0] = wpre[2]; wq[1][1] = wpre[3];
    wq[2][0] = wpre[4]; wq[2][1] = wpre[5];

    bf16x8 xc[2][2];                              // [ks&1][st]
    xc[0][0] = __builtin_bit_cast(bf16x8, *reinterpret_cast<const u32x4*>(xb));
    xc[0][1] = __builtin_bit_cast(bf16x8, *reinterpret_cast<const u32x4*>(xb + 32 * RS));
    xc[1][0] = __builtin_bit_cast(bf16x8, *reinterpret_cast<const u32x4*>(xb + 16));
    xc[1][1] = __builtin_bit_cast(bf16x8, *reinterpret_cast<const u32x4*>(xb + 32 * RS + 16));

#pragma unroll
    for (int ks = 0; ks < NKS; ++ks) {
        const int ws = ks % 3;
        const int xs = ks & 1;
        acc[0][0] = __builtin_amdgcn_mfma_f32_32x32x16_bf16(
            __builtin_bit_cast(bf16x8, wq[ws][0]), xc[xs][0], acc[0][0], 0, 0, 0);
        acc[1][0] = __builtin_amdgcn_mfma_f32_32x32x16_bf16(
            __builtin_bit_cast(bf16x8, wq[ws][1]), xc[xs][0], acc[1][0], 0, 0, 0);
        if (ks + 2 < NKS)
            xc[xs][0] = __builtin_bit_cast(bf16x8,
                *reinterpret_cast<const u32x4*>(xb + (ks + 2) * 16));
        acc[0][1] = __builtin_amdgcn_mfma_f32_32x32x16_bf16(
            __builtin_bit_cast(bf16x8, wq[ws][0]), xc[xs][1], acc[0][1], 0, 0, 0);
        acc[1][1] = __builtin_amdgcn_mfma_f32_32x32x16_bf16(
            __builtin_bit_cast(bf16x8, wq[ws][1]), xc[xs][1], acc[1][1], 0, 0, 0);
        if (ks + 2 < NKS)
            xc[xs][1] = __builtin_bit_cast(bf16x8,
                *reinterpret_cast<const u32x4*>(xb + 32 * RS + (ks + 2) * 16));
        if (ks + 3 < NKS) {
            const u32x4* wn = wbase + (ks + 3) * 512;
            wq[ws][0] = wn[voff];
            wq[ws][1] = wn[voff + 64];
        }
    }

    // Next layer's first-three-kstep fragments: issue now so the L2 latency
    // hides under the epilogue + the inter-layer barrier.
    wnxt[0] = wnb[vnxt];
    wnxt[1] = wnb[vnxt + 64];
    wnxt[2] = wnb[vnxt + nkstr];
    wnxt[3] = wnb[vnxt + nkstr + 64];
    wnxt[4] = wnb[vnxt + 2 * nkstr];
    wnxt[5] = wnb[vnxt + 2 * nkstr + 64];

    // Epilogue: bias + ReLU + bf16, one ds_write_b64 per (ft,q4,st), straight
    // to dst (no barrier needed: dst is not being read this phase).
#pragma unroll
    for (int ft = 0; ft < 2; ++ft) {
        const int fb = wave * 64 + ft * 32 + hi * 4;
#pragma unroll
        for (int q4 = 0; q4 < 4; ++q4) {
            f32x4 bv = *reinterpret_cast<const f32x4*>(bias + fb + q4 * 8);
#pragma unroll
            for (int st = 0; st < 2; ++st) {
                float v0 = fmaxf(acc[ft][st][q4 * 4 + 0] + bv[0], 0.0f);
                float v1 = fmaxf(acc[ft][st][q4 * 4 + 1] + bv[1], 0.0f);
                float v2 = fmaxf(acc[ft][st][q4 * 4 + 2] + bv[2], 0.0f);
                float v3 = fmaxf(acc[ft][st][q4 * 4 + 3] + bv[3], 0.0f);
                __bf16 h0 = (__bf16)v0, h1 = (__bf16)v1, h2 = (__bf16)v2, h3 = (__bf16)v3;
                u32x2 d;
                d[0] = (u32)__builtin_bit_cast(u16, h0) | ((u32)__builtin_bit_cast(u16, h1) << 16);
                d[1] = (u32)__builtin_bit_cast(u16, h2) | ((u32)__builtin_bit_cast(u16, h3) << 16);
                *reinterpret_cast<u32x2*>(db + st * 32 * RS + ft * 32 + q4 * 8) = d;
            }
        }
    }
}

// ---------------------------------------------------------------------------
// Main fused kernel: 16 queries x 4 branches = 64 rows (samples) per block.
// Ping-pong activation buffers (68KB LDS) -> 2 blocks/CU, 1 barrier/layer.
// ---------------------------------------------------------------------------
__global__ __launch_bounds__(256, 2) void liif_main(
    const float* __restrict__ coord, const float* __restrict__ cell,
    const float* __restrict__ b0, const float* __restrict__ b1,
    const float* __restrict__ b2, const float* __restrict__ b3,
    const float* __restrict__ b4,
    const u16* __restrict__ wpack, const u16* __restrict__ featT,
    float* __restrict__ out) {
    __shared__ u16 bufs[2 * 64 * RS];   // 67584 B, ping-pong
    __shared__ float areasLDS[64];

    u16* buf0 = bufs;
    u16* buf1 = bufs + 64 * RS;

    const int t = threadIdx.x;
    const int wave = t >> 6, lane = t & 63;
    const int row = t >> 2, p = t & 3;

    // ---- stage X0 (branch math + feature gather), 4 threads per row ----
    const int bq = blockIdx.x * 16 + (row >> 2);
    const int v = row & 3;
    const int b = bq >> 16;  // Q = 65536
    const float c0 = coord[bq * 2 + 0];
    const float c1 = coord[bq * 2 + 1];
    const float rc0 = cell[bq * 2 + 0] * 128.0f;
    const float rc1 = cell[bq * 2 + 1] * 128.0f;
    const float eps = 1e-6f;
    const float sx = ((v & 2) ? 0.0078125f : -0.0078125f) + eps;
    const float sy = ((v & 1) ? 0.0078125f : -0.0078125f) + eps;
    float cs0 = fminf(fmaxf(c0 + sx, -1.0f + eps), 1.0f - eps);
    float cs1 = fminf(fmaxf(c1 + sy, -1.0f + eps), 1.0f - eps);
    float fy = fminf(fmaxf(floorf((cs0 + 1.0f) * 64.0f), 0.0f), 127.0f);
    float fx = fminf(fmaxf(floorf((cs1 + 1.0f) * 64.0f), 0.0f), 127.0f);
    int iy = (int)fy, ix = (int)fx;
    float qc0 = -1.0f + (2.0f * fy + 1.0f) * 0.0078125f;
    float qc1 = -1.0f + (2.0f * fx + 1.0f) * 0.0078125f;
    float rel0 = (c0 - qc0) * 128.0f;
    float rel1 = (c1 - qc1) * 128.0f;
    float area = fabsf(rel0 * rel1) + 1e-9f;

    {
        const u16* fr = featT + (((b * HH + iy) * WW + ix) * CC) + p * 16;
        u32x4 f0 = *reinterpret_cast<const u32x4*>(fr);
        u32x4 f1 = *reinterpret_cast<const u32x4*>(fr + 8);
        u16* sb = buf0 + row * RS;
        *reinterpret_cast<u32x4*>(sb + p * 16) = f0;
        *reinterpret_cast<u32x4*>(sb + p * 16 + 8) = f1;
        u32x4 e = { 0u, 0u, 0u, 0u };
        if (p == 0) {
            __bf16 h0 = (__bf16)rel0, h1 = (__bf16)rel1, h2 = (__bf16)rc0, h3 = (__bf16)rc1;
            e[0] = (u32)__builtin_bit_cast(u16, h0) | ((u32)__builtin_bit_cast(u16, h1) << 16);
            e[1] = (u32)__builtin_bit_cast(u16, h2) | ((u32)__builtin_bit_cast(u16, h3) << 16);
            areasLDS[row] = area;
        }
        *reinterpret_cast<u32x4*>(sb + 64 + p * 8) = e;  // features 64..95
    }

    const u32x4* wp = reinterpret_cast<const u32x4*>(wpack);
    const u32x4* wp0 = wp + (L0_OFF / 8);
    const u32x4* wp1 = wp + (L1_OFF / 8);
    const u32x4* wp2 = wp + (L2_OFF / 8);
    const u32x4* wp3 = wp + (L3_OFF / 8);
    const u32x4* wp4 = wp + (W4_OFF / 8);
    const int voff = wave * 128 + lane;  // frag(ks=0, nt=wave*2) for 32x32 layers

    u32x4 wA[6], wB[6];
    preload6(wA, wp0, voff, 512);
    __syncthreads();
    gemm32<5>(buf0, buf1, wp0, b0, wave, lane, wA, wB, wp1, voff, 512);
    __syncthreads();
    gemm32<16>(buf1, buf0, wp1, b1, wave, lane, wB, wA, wp2, voff, 512);
    __syncthreads();
    gemm32<16>(buf0, buf1, wp2, b2, wave, lane, wA, wB, wp3, voff, 512);
    __syncthreads();
    // wnb = wp4 with vnxt = lane, nkstr = 128: wB <- w4 frags kt = 0..5
    // (16x16 layout, frag kt at u32x4 offset kt*64).
    gemm32<16>(buf1, buf0, wp3, b3, wave, lane, wB, wA, wp4, lane, 128);
    // w4 kt=6,7 fragments
    u32x4 w4hi[2];
#pragma unroll
    for (int kt = 0; kt < 2; ++kt) w4hi[kt] = wp4[(kt + 6) * 64 + lane];
    __syncthreads();

    // ---- final layer 256->3 via 16x16x32 MFMA; wave handles st = wave ----
    const int l15 = lane & 15;
    const int qd = lane >> 4;
    const u16* xb = buf0 + (wave * 16 + l15) * RS + qd * 8;
    f32x4 accf = {};
#pragma unroll
    for (int kt = 0; kt < 6; ++kt) {
        bf16x8 x = __builtin_bit_cast(bf16x8,
            *reinterpret_cast<const u32x4*>(xb + kt * 32));
        accf = __builtin_amdgcn_mfma_f32_16x16x32_bf16(
            __builtin_bit_cast(bf16x8, wA[kt]), x, accf, 0, 0, 0);
    }
#pragma unroll
    for (int kt = 6; kt < 8; ++kt) {
        bf16x8 x = __builtin_bit_cast(bf16x8,
            *reinterpret_cast<const u32x4*>(xb + kt * 32));
        accf = __builtin_amdgcn_mfma_f32_16x16x32_bf16(
            __builtin_bit_cast(bf16x8, w4hi[kt - 6]), x, accf, 0, 0, 0);
    }
    // lane (qd==0) holds pred[0..2] in accf[0..2] for sample = wave*16 + l15.
    float a = areasLDS[wave * 16 + l15];
    float a1 = a + __shfl_xor(a, 1);
    float asum = a1 + __shfl_xor(a1, 2);
    float aopp = __shfl_xor(a, 3);  // diagonal swap 0<->3, 1<->2
    float wgt = aopp / asum;
    float o0 = (accf[0] + b4[0]) * wgt;
    float o1 = (accf[1] + b4[1]) * wgt;
    float o2 = (accf[2] + b4[2]) * wgt;
    o0 += __shfl_xor(o0, 1); o0 += __shfl_xor(o0, 2);
    o1 += __shfl_xor(o1, 1); o1 += __shfl_xor(o1, 2);
    o2 += __shfl_xor(o2, 1); o2 += __shfl_xor(o2, 2);

    if (qd == 0 && (l15 & 3) == 0) {
        int obq = blockIdx.x * 16 + wave * 4 + (l15 >> 2);
        out[obq * 3 + 0] = o0;
        out[obq * 3 + 1] = o1;
        out[obq * 3 + 2] = o2;
    }
}

// ---------------------------------------------------------------------------
extern "C" void kernel_launch(void* const* d_in, const int* in_sizes, int n_in,
                              void* d_out, int out_size, void* d_ws, size_t ws_size,
                              hipStream_t stream) {
    const float* feat  = (const float*)d_in[0];
    const float* coord = (const float*)d_in[1];
    const float* cell  = (const float*)d_in[2];
    const float* w0 = (const float*)d_in[3];
    const float* b0 = (const float*)d_in[4];
    const float* w1 = (const float*)d_in[5];
    const float* b1 = (const float*)d_in[6];
    const float* w2 = (const float*)d_in[7];
    const float* b2 = (const float*)d_in[8];
    const float* w3 = (const float*)d_in[9];
    const float* b3 = (const float*)d_in[10];
    const float* w4 = (const float*)d_in[11];
    const float* b4 = (const float*)d_in[12];

    u16* ws_us = (u16*)d_ws;
    u16* featT = (u16*)((char*)d_ws + FEATT_BYTE_OFF);
    // ws need: 524288 + 8388608 = 8912896 bytes

    hipLaunchKernelGGL(pack_weights, dim3(432), dim3(64), 0, stream,
                       w0, w1, w2, w3, w4, ws_us);
    hipLaunchKernelGGL(prep_featT, dim3(BB * HH), dim3(256), 0, stream, feat, featT);
    hipLaunchKernelGGL(liif_main, dim3((BB * QQ) / 16), dim3(256), 0, stream,
                       coord, cell, b0, b1, b2, b3, b4, ws_us, featT,
                       (float*)d_out);
}

// Round 4
// 501.989 us; speedup vs baseline: 1.1534x; 1.1534x over previous
//
#include <hip/hip_runtime.h>
#include <cstdint>

typedef __bf16 bf16x8 __attribute__((ext_vector_type(8)));
typedef float f32x4 __attribute__((ext_vector_type(4)));
typedef float f32x16 __attribute__((ext_vector_type(16)));
typedef unsigned int u32x4 __attribute__((ext_vector_type(4)));
typedef unsigned int u32x2 __attribute__((ext_vector_type(2)));
typedef unsigned short u16;
typedef unsigned int u32;

// Problem constants (fixed by reference)
#define HH 128
#define WW 128
#define CC 64
#define QQ 65536
#define BB 4

// LDS activation row stride in u16: 256 features + 8 pad.
// 264 u16 = 132 words; 132 mod 32 = 4 -> rows rotate bank-groups by 4.
// 32-row b128 reads (32x32 B-frags) and b64 epilogue writes are both at the
// LDS phase minimum with this stride. All addresses stay ADDITIVE.
#define RS 264

// Packed-weight offsets in bf16 elements inside d_ws.
// 32x32x16 fragment = 64 lanes x 8 bf16 = 512 elems; frag (ks,nt) at
// (ks*8+nt)*512, nt fastest.  L0: 5 ks x 8 nt = 40; L1-3: 16 x 8 = 128 each.
// w4 keeps the 16x16x32 layout (N=3 pads to 16, not 32): 8 frags.
#define L0_OFF 0        // 40 * 512 = 20480
#define L1_OFF 20480    // 128 * 512 = 65536
#define L2_OFF 86016
#define L3_OFF 151552
#define W4_OFF 217088   // 8 * 512 = 4096 -> total 221184 elems = 442368 B
#define FEATT_BYTE_OFF 524288u  // featT: 4*128*128*64 bf16 = 8388608 B

// ---------------------------------------------------------------------------
// Pack w0..w3 into 32x32x16 MFMA fragment order (bf16):
//   frag (ks,nt): lane l, j=0..7 holds W[ks*16 + (l>>5)*8 + j][nt*32 + (l&31)]
// w4 (256->3) stays in 16x16x32 fragment order (kt-major, NT=1).
// ---------------------------------------------------------------------------
__global__ void pack_weights(const float* __restrict__ w0,
                             const float* __restrict__ w1,
                             const float* __restrict__ w2,
                             const float* __restrict__ w3,
                             const float* __restrict__ w4,
                             u16* __restrict__ ws_us) {
    int bid = blockIdx.x;
    int lane = threadIdx.x;  // 64
    int dst, kbase, n, Ksrc, Ncols;
    const float* w;
    if (bid < 424) {  // 32x32x16 fragments for L0..L3
        int tile, off;
        if (bid < 40)       { tile = bid;       off = L0_OFF; w = w0; Ksrc = 68;  }
        else if (bid < 168) { tile = bid - 40;  off = L1_OFF; w = w1; Ksrc = 256; }
        else if (bid < 296) { tile = bid - 168; off = L2_OFF; w = w2; Ksrc = 256; }
        else                { tile = bid - 296; off = L3_OFF; w = w3; Ksrc = 256; }
        int nt = tile & 7, ks = tile >> 3;
        n = nt * 32 + (lane & 31);
        kbase = ks * 16 + (lane >> 5) * 8;
        Ncols = 256;
        dst = off + tile * 512 + lane * 8;
    } else {          // w4: 16x16x32 fragments, frag kt = bid-424
        int kt = bid - 424;
        n = lane & 15;
        kbase = kt * 32 + (lane >> 4) * 8;
        w = w4; Ksrc = 256; Ncols = 3;
        dst = W4_OFF + kt * 512 + lane * 8;
    }
    unsigned int d[4];
    for (int i = 0; i < 4; ++i) {
        unsigned int lo, hi;
        {
            int k = kbase + 2 * i;
            float x = (k < Ksrc && n < Ncols) ? w[k * Ncols + n] : 0.0f;
            __bf16 hb = (__bf16)x;
            lo = (unsigned int)__builtin_bit_cast(u16, hb);
        }
        {
            int k = kbase + 2 * i + 1;
            float x = (k < Ksrc && n < Ncols) ? w[k * Ncols + n] : 0.0f;
            __bf16 hb = (__bf16)x;
            hi = (unsigned int)__builtin_bit_cast(u16, hb);
        }
        d[i] = lo | (hi << 16);
    }
    u32x4 pk = { d[0], d[1], d[2], d[3] };
    *reinterpret_cast<u32x4*>(ws_us + dst) = pk;
}

// ---------------------------------------------------------------------------
// feat [B,C,H,W] fp32 -> featT [B,H,W,C] bf16 (per-pixel gather = one
// contiguous 128B read). One block per (b, y) row; LDS transpose.
// ---------------------------------------------------------------------------
__global__ void prep_featT(const float* __restrict__ feat, u16* __restrict__ featT) {
    __shared__ u16 tile[128 * 66];
    int bid = blockIdx.x;
    int b = bid >> 7, y = bid & 127;
    for (int idx = threadIdx.x; idx < CC * WW; idx += 256) {
        int c = idx >> 7, x = idx & 127;
        float v = feat[(((b * CC + c) * HH + y) * WW) + x];
        __bf16 hb = (__bf16)v;
        tile[x * 66 + c] = __builtin_bit_cast(u16, hb);
    }
    __syncthreads();
    for (int idx = threadIdx.x; idx < 2048; idx += 256) {
        int x = idx >> 4, c4 = (idx & 15) * 4;
        const u16* src = tile + x * 66 + c4;
        u32x2 d;
        d[0] = (unsigned int)src[0] | ((unsigned int)src[1] << 16);
        d[1] = (unsigned int)src[2] | ((unsigned int)src[3] << 16);
        *reinterpret_cast<u32x2*>(featT + ((b * HH + y) * WW + x) * CC + c4) = d;
    }
}

// ---------------------------------------------------------------------------
// Preload the first THREE ksteps' fragments (6 x 16B) of a layer; issued
// BEFORE a barrier so L2 latency overlaps the barrier wait + epilogue.
// Strides in u32x4 units: kstr = 512 for 32x32 layers (ks stride), 128 for
// the w4 16x16 layout (kt pairs); frag pair within a kstep is +64.
// ---------------------------------------------------------------------------
__device__ __forceinline__ void preload6(u32x4 w[6], const u32x4* __restrict__ b,
                                         int v, int kstr) {
    w[0] = b[v];
    w[1] = b[v + 64];
    w[2] = b[v + kstr];
    w[3] = b[v + kstr + 64];
    w[4] = b[v + 2 * kstr];
    w[5] = b[v + 2 * kstr + 64];
}

// ---------------------------------------------------------------------------
// Transposed GEMM layer via 32x32x16 MFMA, IN-PLACE: Y^T = W^T[256,K]*X^T[K,128].
// 128 samples/block.  Wave = 2 nt x 4 st: features [wave*64, wave*64+64) for
// all 128 samples -> per kstep: 2 weight loads serve 8 MFMAs (each weight
// fragment read once per block -> half the L2 weight stream of the 64-sample
// layout; at MFMA saturation demand ~19 TB/s, under the 34.5 TB/s ceiling).
// Weight frags: wq[3][2] ring (~2.5 ksteps = >1200 cyc cover at 2 waves/SIMD).
// X rows: xc[2][4] ring (~1.5 ksteps cover).  8 independent acc chains/kstep.
// C layout (verified): sample col = lane&31, feature row =
// (reg&3) + 8*(reg>>2) + 4*(lane>>5).
// ---------------------------------------------------------------------------
template <int NKS>
__device__ __forceinline__ void gemm32(u16* buf,
                                       const u32x4* __restrict__ wbase,
                                       const float* __restrict__ bias,
                                       int wave, int lane,
                                       const u32x4 wpre[6],
                                       u32x4 wnxt[6],
                                       const u32x4* __restrict__ wnb,
                                       int vnxt, int nkstr) {
    f32x16 acc[2][4] = {};                        // [ft][st]
    const int l31 = lane & 31;
    const int hi = lane >> 5;
    const int voff = wave * 128 + lane;           // u32x4 index of frag(ks=0, nt=wave*2)
    const u16* xb = buf + l31 * RS + hi * 8;      // one LDS base for ALL reads
    u16* db = buf + l31 * RS + wave * 64 + hi * 4;

    u32x4 wq[3][2];
    wq[0][0] = wpre[0]; wq[0][1] = wpre[1];
    wq[1][0] = wpre[2]; wq[1][1] = wpre[3];
    wq[2][0] = wpre[4]; wq[2][1] = wpre[5];

    bf16x8 xc[2][4];                              // [ks&1][st]
#pragma unroll
    for (int st = 0; st < 4; ++st) {
        xc[0][st] = __builtin_bit_cast(bf16x8,
            *reinterpret_cast<const u32x4*>(xb + st * 32 * RS));
        xc[1][st] = __builtin_bit_cast(bf16x8,
            *reinterpret_cast<const u32x4*>(xb + st * 32 * RS + 16));
    }

#pragma unroll
    for (int ks = 0; ks < NKS; ++ks) {
        const int ws = ks % 3;
        const int xs = ks & 1;
#pragma unroll
        for (int st = 0; st < 4; ++st) {
            acc[0][st] = __builtin_amdgcn_mfma_f32_32x32x16_bf16(
                __builtin_bit_cast(bf16x8, wq[ws][0]), xc[xs][st], acc[0][st], 0, 0, 0);
            acc[1][st] = __builtin_amdgcn_mfma_f32_32x32x16_bf16(
                __builtin_bit_cast(bf16x8, wq[ws][1]), xc[xs][st], acc[1][st], 0, 0, 0);
            if (ks + 2 < NKS)
                xc[xs][st] = __builtin_bit_cast(bf16x8,
                    *reinterpret_cast<const u32x4*>(xb + st * 32 * RS + (ks + 2) * 16));
        }
        if (ks + 3 < NKS) {
            const u32x4* wn = wbase + (ks + 3) * 512;
            wq[ws][0] = wn[voff];
            wq[ws][1] = wn[voff + 64];
        }
    }

    // Next layer's first-three-kstep fragments: issue before the read-drain
    // barrier so the L2 latency hides under the barrier + epilogue.
    wnxt[0] = wnb[vnxt];
    wnxt[1] = wnb[vnxt + 64];
    wnxt[2] = wnb[vnxt + nkstr];
    wnxt[3] = wnb[vnxt + nkstr + 64];
    wnxt[4] = wnb[vnxt + 2 * nkstr];
    wnxt[5] = wnb[vnxt + 2 * nkstr + 64];

    __syncthreads();  // all waves' reads of buf complete -> in-place write OK

    // Epilogue: bias + ReLU + bf16, one ds_write_b64 per (ft,q4,st), imm offs.
#pragma unroll
    for (int ft = 0; ft < 2; ++ft) {
        const int fb = wave * 64 + ft * 32 + hi * 4;
#pragma unroll
        for (int q4 = 0; q4 < 4; ++q4) {
            f32x4 bv = *reinterpret_cast<const f32x4*>(bias + fb + q4 * 8);
#pragma unroll
            for (int st = 0; st < 4; ++st) {
                float v0 = fmaxf(acc[ft][st][q4 * 4 + 0] + bv[0], 0.0f);
                float v1 = fmaxf(acc[ft][st][q4 * 4 + 1] + bv[1], 0.0f);
                float v2 = fmaxf(acc[ft][st][q4 * 4 + 2] + bv[2], 0.0f);
                float v3 = fmaxf(acc[ft][st][q4 * 4 + 3] + bv[3], 0.0f);
                __bf16 h0 = (__bf16)v0, h1 = (__bf16)v1, h2 = (__bf16)v2, h3 = (__bf16)v3;
                u32x2 d;
                d[0] = (u32)__builtin_bit_cast(u16, h0) | ((u32)__builtin_bit_cast(u16, h1) << 16);
                d[1] = (u32)__builtin_bit_cast(u16, h2) | ((u32)__builtin_bit_cast(u16, h3) << 16);
                *reinterpret_cast<u32x2*>(db + st * 32 * RS + ft * 32 + q4 * 8) = d;
            }
        }
    }
}

// ---------------------------------------------------------------------------
// Main fused kernel: 32 queries x 4 branches = 128 rows (samples) per block.
// Single 67.6KB activation buffer (in-place layers) -> 2 blocks/CU.
// ---------------------------------------------------------------------------
__global__ __launch_bounds__(256, 2) void liif_main(
    const float* __restrict__ coord, const float* __restrict__ cell,
    const float* __restrict__ b0, const float* __restrict__ b1,
    const float* __restrict__ b2, const float* __restrict__ b3,
    const float* __restrict__ b4,
    const u16* __restrict__ wpack, const u16* __restrict__ featT,
    float* __restrict__ out) {
    __shared__ u16 bufA[128 * RS];   // 67584 B
    __shared__ float areasLDS[128];

    const int t = threadIdx.x;
    const int wave = t >> 6, lane = t & 63;
    const int row = t >> 1, p = t & 1;   // 128 rows, 2 threads per row

    // ---- stage X0 (branch math + feature gather), 2 threads per row ----
    const int bq = blockIdx.x * 32 + (row >> 2);
    const int v = row & 3;
    const int b = bq >> 16;  // Q = 65536
    const float c0 = coord[bq * 2 + 0];
    const float c1 = coord[bq * 2 + 1];
    const float rc0 = cell[bq * 2 + 0] * 128.0f;
    const float rc1 = cell[bq * 2 + 1] * 128.0f;
    const float eps = 1e-6f;
    const float sx = ((v & 2) ? 0.0078125f : -0.0078125f) + eps;
    const float sy = ((v & 1) ? 0.0078125f : -0.0078125f) + eps;
    float cs0 = fminf(fmaxf(c0 + sx, -1.0f + eps), 1.0f - eps);
    float cs1 = fminf(fmaxf(c1 + sy, -1.0f + eps), 1.0f - eps);
    float fy = fminf(fmaxf(floorf((cs0 + 1.0f) * 64.0f), 0.0f), 127.0f);
    float fx = fminf(fmaxf(floorf((cs1 + 1.0f) * 64.0f), 0.0f), 127.0f);
    int iy = (int)fy, ix = (int)fx;
    float qc0 = -1.0f + (2.0f * fy + 1.0f) * 0.0078125f;
    float qc1 = -1.0f + (2.0f * fx + 1.0f) * 0.0078125f;
    float rel0 = (c0 - qc0) * 128.0f;
    float rel1 = (c1 - qc1) * 128.0f;
    float area = fabsf(rel0 * rel1) + 1e-9f;

    {
        // 32 features per thread (4 x b128)
        const u16* fr = featT + (((b * HH + iy) * WW + ix) * CC) + p * 32;
        u32x4 f0 = *reinterpret_cast<const u32x4*>(fr);
        u32x4 f1 = *reinterpret_cast<const u32x4*>(fr + 8);
        u32x4 f2 = *reinterpret_cast<const u32x4*>(fr + 16);
        u32x4 f3 = *reinterpret_cast<const u32x4*>(fr + 24);
        u16* sb = bufA + row * RS;
        *reinterpret_cast<u32x4*>(sb + p * 32) = f0;
        *reinterpret_cast<u32x4*>(sb + p * 32 + 8) = f1;
        *reinterpret_cast<u32x4*>(sb + p * 32 + 16) = f2;
        *reinterpret_cast<u32x4*>(sb + p * 32 + 24) = f3;
        u32x4 e = { 0u, 0u, 0u, 0u };
        u32x4 z = { 0u, 0u, 0u, 0u };
        if (p == 0) {
            __bf16 h0 = (__bf16)rel0, h1 = (__bf16)rel1, h2 = (__bf16)rc0, h3 = (__bf16)rc1;
            e[0] = (u32)__builtin_bit_cast(u16, h0) | ((u32)__builtin_bit_cast(u16, h1) << 16);
            e[1] = (u32)__builtin_bit_cast(u16, h2) | ((u32)__builtin_bit_cast(u16, h3) << 16);
            areasLDS[row] = area;
        }
        // features 64..95 (reals in first 4 of p==0's chunk, zeros elsewhere)
        *reinterpret_cast<u32x4*>(sb + 64 + p * 16) = e;
        *reinterpret_cast<u32x4*>(sb + 64 + p * 16 + 8) = z;
    }

    const u32x4* wp = reinterpret_cast<const u32x4*>(wpack);
    const u32x4* wp0 = wp + (L0_OFF / 8);
    const u32x4* wp1 = wp + (L1_OFF / 8);
    const u32x4* wp2 = wp + (L2_OFF / 8);
    const u32x4* wp3 = wp + (L3_OFF / 8);
    const u32x4* wp4 = wp + (W4_OFF / 8);
    const int voff = wave * 128 + lane;  // frag(ks=0, nt=wave*2) for 32x32 layers

    u32x4 wA[6], wB[6];
    preload6(wA, wp0, voff, 512);
    __syncthreads();
    gemm32<5>(bufA, wp0, b0, wave, lane, wA, wB, wp1, voff, 512);
    __syncthreads();
    gemm32<16>(bufA, wp1, b1, wave, lane, wB, wA, wp2, voff, 512);
    __syncthreads();
    gemm32<16>(bufA, wp2, b2, wave, lane, wA, wB, wp3, voff, 512);
    __syncthreads();
    // wnb = wp4 with vnxt = lane, nkstr = 128: wB <- w4 frags kt = 0..5
    // (16x16 layout, frag kt at u32x4 offset kt*64).
    gemm32<16>(bufA, wp3, b3, wave, lane, wB, wA, wp4, lane, 128);
    // w4 kt=6,7 fragments
    u32x4 w4hi[2];
#pragma unroll
    for (int kt = 0; kt < 2; ++kt) w4hi[kt] = wp4[(kt + 6) * 64 + lane];
    __syncthreads();

    // ---- final layer 256->3 via 16x16x32 MFMA; wave handles 2 st tiles ----
    const int l15 = lane & 15;
    const int qd = lane >> 4;
    const u16* xb4 = bufA + (wave * 32 + l15) * RS + qd * 8;
    f32x4 accf[2] = {};
#pragma unroll
    for (int kt = 0; kt < 8; ++kt) {
        bf16x8 a = __builtin_bit_cast(bf16x8, (kt < 6) ? wA[kt] : w4hi[kt - 6]);
        bf16x8 x0 = __builtin_bit_cast(bf16x8,
            *reinterpret_cast<const u32x4*>(xb4 + kt * 32));
        accf[0] = __builtin_amdgcn_mfma_f32_16x16x32_bf16(a, x0, accf[0], 0, 0, 0);
        bf16x8 x1 = __builtin_bit_cast(bf16x8,
            *reinterpret_cast<const u32x4*>(xb4 + 16 * RS + kt * 32));
        accf[1] = __builtin_amdgcn_mfma_f32_16x16x32_bf16(a, x1, accf[1], 0, 0, 0);
    }
    // lane (qd==0) holds pred[0..2] for samples wave*32 + stl*16 + l15.
#pragma unroll
    for (int stl = 0; stl < 2; ++stl) {
        float a = areasLDS[wave * 32 + stl * 16 + l15];
        float a1 = a + __shfl_xor(a, 1);
        float asum = a1 + __shfl_xor(a1, 2);
        float aopp = __shfl_xor(a, 3);  // diagonal swap 0<->3, 1<->2
        float wgt = aopp / asum;
        float o0 = (accf[stl][0] + b4[0]) * wgt;
        float o1 = (accf[stl][1] + b4[1]) * wgt;
        float o2 = (accf[stl][2] + b4[2]) * wgt;
        o0 += __shfl_xor(o0, 1); o0 += __shfl_xor(o0, 2);
        o1 += __shfl_xor(o1, 1); o1 += __shfl_xor(o1, 2);
        o2 += __shfl_xor(o2, 1); o2 += __shfl_xor(o2, 2);
        if (qd == 0 && (l15 & 3) == 0) {
            int obq = blockIdx.x * 32 + wave * 8 + stl * 4 + (l15 >> 2);
            out[obq * 3 + 0] = o0;
            out[obq * 3 + 1] = o1;
            out[obq * 3 + 2] = o2;
        }
    }
}

// ---------------------------------------------------------------------------
extern "C" void kernel_launch(void* const* d_in, const int* in_sizes, int n_in,
                              void* d_out, int out_size, void* d_ws, size_t ws_size,
                              hipStream_t stream) {
    const float* feat  = (const float*)d_in[0];
    const float* coord = (const float*)d_in[1];
    const float* cell  = (const float*)d_in[2];
    const float* w0 = (const float*)d_in[3];
    const float* b0 = (const float*)d_in[4];
    const float* w1 = (const float*)d_in[5];
    const float* b1 = (const float*)d_in[6];
    const float* w2 = (const float*)d_in[7];
    const float* b2 = (const float*)d_in[8];
    const float* w3 = (const float*)d_in[9];
    const float* b3 = (const float*)d_in[10];
    const float* w4 = (const float*)d_in[11];
    const float* b4 = (const float*)d_in[12];

    u16* ws_us = (u16*)d_ws;
    u16* featT = (u16*)((char*)d_ws + FEATT_BYTE_OFF);
    // ws need: 524288 + 8388608 = 8912896 bytes

    hipLaunchKernelGGL(pack_weights, dim3(432), dim3(64), 0, stream,
                       w0, w1, w2, w3, w4, ws_us);
    hipLaunchKernelGGL(prep_featT, dim3(BB * HH), dim3(256), 0, stream, feat, featT);
    hipLaunchKernelGGL(liif_main, dim3((BB * QQ) / 32), dim3(256), 0, stream,
                       coord, cell, b0, b1, b2, b3, b4, ws_us, featT,
                       (float*)d_out);
}

// Round 5
// 487.929 us; speedup vs baseline: 1.1866x; 1.0288x over previous
//
#include <hip/hip_runtime.h>
#include <cstdint>

typedef __bf16 bf16x8 __attribute__((ext_vector_type(8)));
typedef float f32x4 __attribute__((ext_vector_type(4)));
typedef float f32x16 __attribute__((ext_vector_type(16)));
typedef unsigned int u32x4 __attribute__((ext_vector_type(4)));
typedef unsigned int u32x2 __attribute__((ext_vector_type(2)));
typedef unsigned short u16;
typedef unsigned int u32;

// Problem constants (fixed by reference)
#define HH 128
#define WW 128
#define CC 64
#define QQ 65536
#define BB 4

// LDS activation row stride in u16: 256 features + 8 pad.
// 264 u16 = 132 words; 132 mod 32 = 4 -> rows rotate bank-groups by 4.
// 32-row b128 reads (32x32 B-frags) and b64 epilogue writes are both at the
// LDS phase minimum with this stride. All addresses stay ADDITIVE.
#define RS 264

// Packed-weight offsets in bf16 elements inside d_ws.
// 32x32x16 fragment = 64 lanes x 8 bf16 = 512 elems; frag (ks,nt) at
// (ks*8+nt)*512, nt fastest.  L0: 5 ks x 8 nt = 40; L1-3: 16 x 8 = 128 each.
// w4 keeps the 16x16x32 layout (N=3 pads to 16, not 32): 8 frags.
#define L0_OFF 0        // 40 * 512 = 20480
#define L1_OFF 20480    // 128 * 512 = 65536
#define L2_OFF 86016
#define L3_OFF 151552
#define W4_OFF 217088   // 8 * 512 = 4096 -> total 221184 elems = 442368 B
#define FEATT_BYTE_OFF 524288u  // featT: 4*128*128*64 bf16 = 8388608 B

// ---------------------------------------------------------------------------
// Pack w0..w3 into 32x32x16 MFMA fragment order (bf16):
//   frag (ks,nt): lane l, j=0..7 holds W[ks*16 + (l>>5)*8 + j][nt*32 + (l&31)]
// w4 (256->3) stays in 16x16x32 fragment order (kt-major, NT=1).
// ---------------------------------------------------------------------------
__global__ void pack_weights(const float* __restrict__ w0,
                             const float* __restrict__ w1,
                             const float* __restrict__ w2,
                             const float* __restrict__ w3,
                             const float* __restrict__ w4,
                             u16* __restrict__ ws_us) {
    int bid = blockIdx.x;
    int lane = threadIdx.x;  // 64
    int dst, kbase, n, Ksrc, Ncols;
    const float* w;
    if (bid < 424) {  // 32x32x16 fragments for L0..L3
        int tile, off;
        if (bid < 40)       { tile = bid;       off = L0_OFF; w = w0; Ksrc = 68;  }
        else if (bid < 168) { tile = bid - 40;  off = L1_OFF; w = w1; Ksrc = 256; }
        else if (bid < 296) { tile = bid - 168; off = L2_OFF; w = w2; Ksrc = 256; }
        else                { tile = bid - 296; off = L3_OFF; w = w3; Ksrc = 256; }
        int nt = tile & 7, ks = tile >> 3;
        n = nt * 32 + (lane & 31);
        kbase = ks * 16 + (lane >> 5) * 8;
        Ncols = 256;
        dst = off + tile * 512 + lane * 8;
    } else {          // w4: 16x16x32 fragments, frag kt = bid-424
        int kt = bid - 424;
        n = lane & 15;
        kbase = kt * 32 + (lane >> 4) * 8;
        w = w4; Ksrc = 256; Ncols = 3;
        dst = W4_OFF + kt * 512 + lane * 8;
    }
    unsigned int d[4];
    for (int i = 0; i < 4; ++i) {
        unsigned int lo, hi;
        {
            int k = kbase + 2 * i;
            float x = (k < Ksrc && n < Ncols) ? w[k * Ncols + n] : 0.0f;
            __bf16 hb = (__bf16)x;
            lo = (unsigned int)__builtin_bit_cast(u16, hb);
        }
        {
            int k = kbase + 2 * i + 1;
            float x = (k < Ksrc && n < Ncols) ? w[k * Ncols + n] : 0.0f;
            __bf16 hb = (__bf16)x;
            hi = (unsigned int)__builtin_bit_cast(u16, hb);
        }
        d[i] = lo | (hi << 16);
    }
    u32x4 pk = { d[0], d[1], d[2], d[3] };
    *reinterpret_cast<u32x4*>(ws_us + dst) = pk;
}

// ---------------------------------------------------------------------------
// feat [B,C,H,W] fp32 -> featT [B,H,W,C] bf16 (per-pixel gather = one
// contiguous 128B read). One block per (b, y) row; LDS transpose.
// ---------------------------------------------------------------------------
__global__ void prep_featT(const float* __restrict__ feat, u16* __restrict__ featT) {
    __shared__ u16 tile[128 * 66];
    int bid = blockIdx.x;
    int b = bid >> 7, y = bid & 127;
    for (int idx = threadIdx.x; idx < CC * WW; idx += 256) {
        int c = idx >> 7, x = idx & 127;
        float v = feat[(((b * CC + c) * HH + y) * WW) + x];
        __bf16 hb = (__bf16)v;
        tile[x * 66 + c] = __builtin_bit_cast(u16, hb);
    }
    __syncthreads();
    for (int idx = threadIdx.x; idx < 2048; idx += 256) {
        int x = idx >> 4, c4 = (idx & 15) * 4;
        const u16* src = tile + x * 66 + c4;
        u32x2 d;
        d[0] = (unsigned int)src[0] | ((unsigned int)src[1] << 16);
        d[1] = (unsigned int)src[2] | ((unsigned int)src[3] << 16);
        *reinterpret_cast<u32x2*>(featT + ((b * HH + y) * WW + x) * CC + c4) = d;
    }
}

// ---------------------------------------------------------------------------
// Preload the first THREE ksteps' fragments (6 x 16B) of a layer; issued
// BEFORE a barrier so L2 latency overlaps the barrier wait + epilogue.
// ---------------------------------------------------------------------------
__device__ __forceinline__ void preload6(u32x4 w[6], const u32x4* __restrict__ b,
                                         int v, int kstr) {
    w[0] = b[v];
    w[1] = b[v + 64];
    w[2] = b[v + kstr];
    w[3] = b[v + kstr + 64];
    w[4] = b[v + 2 * kstr];
    w[5] = b[v + 2 * kstr + 64];
}

// ---------------------------------------------------------------------------
// Transposed GEMM layer via 32x32x16 MFMA, IN-PLACE: Y^T = W^T[256,K]*X^T[K,128].
// 128 samples/block.  Wave = 2 nt x 4 st.  Weight ring wq[3][2]; X ring
// xc[2][4].  ACC IS INITIALIZED WITH BIAS (from a 4KB LDS bias table) so the
// epilogue is only relu + cvt_pk_bf16 + ds_write (VALU phase is the uncovered
// term per r4 counters: MfmaUtil 51 + VALUBusy 41 = 92%).
// C layout (verified): sample col = lane&31, feature row =
// (reg&3) + 8*(reg>>2) + 4*(lane>>5).
// ---------------------------------------------------------------------------
template <int NKS>
__device__ __forceinline__ void gemm32(u16* buf,
                                       const u32x4* __restrict__ wbase,
                                       const float* biasL,   // LDS, 256 floats
                                       int wave, int lane,
                                       const u32x4 wpre[6],
                                       u32x4 wnxt[6],
                                       const u32x4* __restrict__ wnb,
                                       int vnxt, int nkstr) {
    const int l31 = lane & 31;
    const int hi = lane >> 5;
    const int voff = wave * 128 + lane;           // u32x4 index of frag(ks=0, nt=wave*2)
    const u16* xb = buf + l31 * RS + hi * 8;      // one LDS base for ALL reads
    u16* db = buf + l31 * RS + wave * 64 + hi * 4;

    // acc init = bias (feature row (r&3)+8*(r>>2)+4*hi) -> epilogue loses the add.
    f32x16 binit[2];
#pragma unroll
    for (int ft = 0; ft < 2; ++ft) {
#pragma unroll
        for (int q4 = 0; q4 < 4; ++q4) {
            f32x4 bv = *reinterpret_cast<const f32x4*>(
                biasL + wave * 64 + ft * 32 + q4 * 8 + hi * 4);
            binit[ft][q4 * 4 + 0] = bv[0];
            binit[ft][q4 * 4 + 1] = bv[1];
            binit[ft][q4 * 4 + 2] = bv[2];
            binit[ft][q4 * 4 + 3] = bv[3];
        }
    }
    f32x16 acc[2][4];                             // [ft][st]
#pragma unroll
    for (int ft = 0; ft < 2; ++ft)
#pragma unroll
        for (int st = 0; st < 4; ++st) acc[ft][st] = binit[ft];

    u32x4 wq[3][2];
    wq[0][0] = wpre[0]; wq[0][1] = wpre[1];
    wq[1][0] = wpre[2]; wq[1][1] = wpre[3];
    wq[2][0] = wpre[4]; wq[2][1] = wpre[5];

    bf16x8 xc[2][4];                              // [ks&1][st]
#pragma unroll
    for (int st = 0; st < 4; ++st) {
        xc[0][st] = __builtin_bit_cast(bf16x8,
            *reinterpret_cast<const u32x4*>(xb + st * 32 * RS));
        xc[1][st] = __builtin_bit_cast(bf16x8,
            *reinterpret_cast<const u32x4*>(xb + st * 32 * RS + 16));
    }

    __builtin_amdgcn_s_setprio(1);                // favor the MFMA phase (T5)
#pragma unroll
    for (int ks = 0; ks < NKS; ++ks) {
        const int ws = ks % 3;
        const int xs = ks & 1;
#pragma unroll
        for (int st = 0; st < 4; ++st) {
            acc[0][st] = __builtin_amdgcn_mfma_f32_32x32x16_bf16(
                __builtin_bit_cast(bf16x8, wq[ws][0]), xc[xs][st], acc[0][st], 0, 0, 0);
            acc[1][st] = __builtin_amdgcn_mfma_f32_32x32x16_bf16(
                __builtin_bit_cast(bf16x8, wq[ws][1]), xc[xs][st], acc[1][st], 0, 0, 0);
            if (ks + 2 < NKS)
                xc[xs][st] = __builtin_bit_cast(bf16x8,
                    *reinterpret_cast<const u32x4*>(xb + st * 32 * RS + (ks + 2) * 16));
        }
        if (ks + 3 < NKS) {
            const u32x4* wn = wbase + (ks + 3) * 512;
            wq[ws][0] = wn[voff];
            wq[ws][1] = wn[voff + 64];
        }
    }
    __builtin_amdgcn_s_setprio(0);

    // Next layer's first-three-kstep fragments: issue before the read-drain
    // barrier so the L2 latency hides under the barrier + epilogue.
    wnxt[0] = wnb[vnxt];
    wnxt[1] = wnb[vnxt + 64];
    wnxt[2] = wnb[vnxt + nkstr];
    wnxt[3] = wnb[vnxt + nkstr + 64];
    wnxt[4] = wnb[vnxt + 2 * nkstr];
    wnxt[5] = wnb[vnxt + 2 * nkstr + 64];

    __syncthreads();  // all waves' reads of buf complete -> in-place write OK

    // Epilogue: relu + packed bf16 cvt (v_cvt_pk_bf16_f32) + ds_write_b64.
#pragma unroll
    for (int ft = 0; ft < 2; ++ft) {
#pragma unroll
        for (int st = 0; st < 4; ++st) {
#pragma unroll
            for (int q4 = 0; q4 < 4; ++q4) {
                float v0 = fmaxf(acc[ft][st][q4 * 4 + 0], 0.0f);
                float v1 = fmaxf(acc[ft][st][q4 * 4 + 1], 0.0f);
                float v2 = fmaxf(acc[ft][st][q4 * 4 + 2], 0.0f);
                float v3 = fmaxf(acc[ft][st][q4 * 4 + 3], 0.0f);
                u32 lo, hi2;
                asm("v_cvt_pk_bf16_f32 %0, %1, %2" : "=v"(lo)  : "v"(v0), "v"(v1));
                asm("v_cvt_pk_bf16_f32 %0, %1, %2" : "=v"(hi2) : "v"(v2), "v"(v3));
                u32x2 d = { lo, hi2 };
                *reinterpret_cast<u32x2*>(db + st * 32 * RS + ft * 32 + q4 * 8) = d;
            }
        }
    }
}

// ---------------------------------------------------------------------------
// Main fused kernel: 32 queries x 4 branches = 128 rows (samples) per block.
// Single 67.6KB activation buffer (in-place layers) + 4KB LDS bias table
// -> 2 blocks/CU.
// ---------------------------------------------------------------------------
__global__ __launch_bounds__(256, 2) void liif_main(
    const float* __restrict__ coord, const float* __restrict__ cell,
    const float* __restrict__ b0, const float* __restrict__ b1,
    const float* __restrict__ b2, const float* __restrict__ b3,
    const float* __restrict__ b4,
    const u16* __restrict__ wpack, const u16* __restrict__ featT,
    float* __restrict__ out) {
    __shared__ u16 bufA[128 * RS];   // 67584 B
    __shared__ float biasLDS[4 * 256];
    __shared__ float areasLDS[128];

    const int t = threadIdx.x;
    const int wave = t >> 6, lane = t & 63;
    const int row = t >> 1, p = t & 1;   // 128 rows, 2 threads per row

    // ---- stage bias table (b0..b3 -> LDS) ----
    biasLDS[t]       = b0[t];
    biasLDS[256 + t] = b1[t];
    biasLDS[512 + t] = b2[t];
    biasLDS[768 + t] = b3[t];

    // ---- stage X0 (branch math + feature gather), 2 threads per row ----
    const int bq = blockIdx.x * 32 + (row >> 2);
    const int v = row & 3;
    const int b = bq >> 16;  // Q = 65536
    const float c0 = coord[bq * 2 + 0];
    const float c1 = coord[bq * 2 + 1];
    const float rc0 = cell[bq * 2 + 0] * 128.0f;
    const float rc1 = cell[bq * 2 + 1] * 128.0f;
    const float eps = 1e-6f;
    const float sx = ((v & 2) ? 0.0078125f : -0.0078125f) + eps;
    const float sy = ((v & 1) ? 0.0078125f : -0.0078125f) + eps;
    float cs0 = fminf(fmaxf(c0 + sx, -1.0f + eps), 1.0f - eps);
    float cs1 = fminf(fmaxf(c1 + sy, -1.0f + eps), 1.0f - eps);
    float fy = fminf(fmaxf(floorf((cs0 + 1.0f) * 64.0f), 0.0f), 127.0f);
    float fx = fminf(fmaxf(floorf((cs1 + 1.0f) * 64.0f), 0.0f), 127.0f);
    int iy = (int)fy, ix = (int)fx;
    float qc0 = -1.0f + (2.0f * fy + 1.0f) * 0.0078125f;
    float qc1 = -1.0f + (2.0f * fx + 1.0f) * 0.0078125f;
    float rel0 = (c0 - qc0) * 128.0f;
    float rel1 = (c1 - qc1) * 128.0f;
    float area = fabsf(rel0 * rel1) + 1e-9f;

    {
        // 32 features per thread (4 x b128)
        const u16* fr = featT + (((b * HH + iy) * WW + ix) * CC) + p * 32;
        u32x4 f0 = *reinterpret_cast<const u32x4*>(fr);
        u32x4 f1 = *reinterpret_cast<const u32x4*>(fr + 8);
        u32x4 f2 = *reinterpret_cast<const u32x4*>(fr + 16);
        u32x4 f3 = *reinterpret_cast<const u32x4*>(fr + 24);
        u16* sb = bufA + row * RS;
        *reinterpret_cast<u32x4*>(sb + p * 32) = f0;
        *reinterpret_cast<u32x4*>(sb + p * 32 + 8) = f1;
        *reinterpret_cast<u32x4*>(sb + p * 32 + 16) = f2;
        *reinterpret_cast<u32x4*>(sb + p * 32 + 24) = f3;
        u32x4 e = { 0u, 0u, 0u, 0u };
        u32x4 z = { 0u, 0u, 0u, 0u };
        if (p == 0) {
            __bf16 h0 = (__bf16)rel0, h1 = (__bf16)rel1, h2 = (__bf16)rc0, h3 = (__bf16)rc1;
            e[0] = (u32)__builtin_bit_cast(u16, h0) | ((u32)__builtin_bit_cast(u16, h1) << 16);
            e[1] = (u32)__builtin_bit_cast(u16, h2) | ((u32)__builtin_bit_cast(u16, h3) << 16);
            areasLDS[row] = area;
        }
        // features 64..95 (reals in first 4 of p==0's chunk, zeros elsewhere)
        *reinterpret_cast<u32x4*>(sb + 64 + p * 16) = e;
        *reinterpret_cast<u32x4*>(sb + 64 + p * 16 + 8) = z;
    }

    const u32x4* wp = reinterpret_cast<const u32x4*>(wpack);
    const u32x4* wp0 = wp + (L0_OFF / 8);
    const u32x4* wp1 = wp + (L1_OFF / 8);
    const u32x4* wp2 = wp + (L2_OFF / 8);
    const u32x4* wp3 = wp + (L3_OFF / 8);
    const u32x4* wp4 = wp + (W4_OFF / 8);
    const int voff = wave * 128 + lane;  // frag(ks=0, nt=wave*2) for 32x32 layers

    u32x4 wA[6], wB[6];
    preload6(wA, wp0, voff, 512);
    __syncthreads();
    gemm32<5>(bufA, wp0, biasLDS, wave, lane, wA, wB, wp1, voff, 512);
    __syncthreads();
    gemm32<16>(bufA, wp1, biasLDS + 256, wave, lane, wB, wA, wp2, voff, 512);
    __syncthreads();
    gemm32<16>(bufA, wp2, biasLDS + 512, wave, lane, wA, wB, wp3, voff, 512);
    __syncthreads();
    // wnb = wp4 with vnxt = lane, nkstr = 128: wB <- w4 frags kt = 0..5
    // (16x16 layout, frag kt at u32x4 offset kt*64).
    gemm32<16>(bufA, wp3, biasLDS + 768, wave, lane, wB, wA, wp4, lane, 128);
    // w4 kt=6,7 fragments
    u32x4 w4hi[2];
#pragma unroll
    for (int kt = 0; kt < 2; ++kt) w4hi[kt] = wp4[(kt + 6) * 64 + lane];
    __syncthreads();

    // ---- final layer 256->3 via 16x16x32 MFMA; wave handles 2 st tiles ----
    const int l15 = lane & 15;
    const int qd = lane >> 4;
    const u16* xb4 = bufA + (wave * 32 + l15) * RS + qd * 8;
    f32x4 accf[2] = {};
#pragma unroll
    for (int kt = 0; kt < 8; ++kt) {
        bf16x8 a = __builtin_bit_cast(bf16x8, (kt < 6) ? wA[kt] : w4hi[kt - 6]);
        bf16x8 x0 = __builtin_bit_cast(bf16x8,
            *reinterpret_cast<const u32x4*>(xb4 + kt * 32));
        accf[0] = __builtin_amdgcn_mfma_f32_16x16x32_bf16(a, x0, accf[0], 0, 0, 0);
        bf16x8 x1 = __builtin_bit_cast(bf16x8,
            *reinterpret_cast<const u32x4*>(xb4 + 16 * RS + kt * 32));
        accf[1] = __builtin_amdgcn_mfma_f32_16x16x32_bf16(a, x1, accf[1], 0, 0, 0);
    }
    // lane (qd==0) holds pred[0..2] for samples wave*32 + stl*16 + l15.
#pragma unroll
    for (int stl = 0; stl < 2; ++stl) {
        float a = areasLDS[wave * 32 + stl * 16 + l15];
        float a1 = a + __shfl_xor(a, 1);
        float asum = a1 + __shfl_xor(a1, 2);
        float aopp = __shfl_xor(a, 3);  // diagonal swap 0<->3, 1<->2
        float wgt = aopp / asum;
        float o0 = (accf[stl][0] + b4[0]) * wgt;
        float o1 = (accf[stl][1] + b4[1]) * wgt;
        float o2 = (accf[stl][2] + b4[2]) * wgt;
        o0 += __shfl_xor(o0, 1); o0 += __shfl_xor(o0, 2);
        o1 += __shfl_xor(o1, 1); o1 += __shfl_xor(o1, 2);
        o2 += __shfl_xor(o2, 1); o2 += __shfl_xor(o2, 2);
        if (qd == 0 && (l15 & 3) == 0) {
            int obq = blockIdx.x * 32 + wave * 8 + stl * 4 + (l15 >> 2);
            out[obq * 3 + 0] = o0;
            out[obq * 3 + 1] = o1;
            out[obq * 3 + 2] = o2;
        }
    }
}

// ---------------------------------------------------------------------------
extern "C" void kernel_launch(void* const* d_in, const int* in_sizes, int n_in,
                              void* d_out, int out_size, void* d_ws, size_t ws_size,
                              hipStream_t stream) {
    const float* feat  = (const float*)d_in[0];
    const float* coord = (const float*)d_in[1];
    const float* cell  = (const float*)d_in[2];
    const float* w0 = (const float*)d_in[3];
    const float* b0 = (const float*)d_in[4];
    const float* w1 = (const float*)d_in[5];
    const float* b1 = (const float*)d_in[6];
    const float* w2 = (const float*)d_in[7];
    const float* b2 = (const float*)d_in[8];
    const float* w3 = (const float*)d_in[9];
    const float* b3 = (const float*)d_in[10];
    const float* w4 = (const float*)d_in[11];
    const float* b4 = (const float*)d_in[12];

    u16* ws_us = (u16*)d_ws;
    u16* featT = (u16*)((char*)d_ws + FEATT_BYTE_OFF);
    // ws need: 524288 + 8388608 = 8912896 bytes

    hipLaunchKernelGGL(pack_weights, dim3(432), dim3(64), 0, stream,
                       w0, w1, w2, w3, w4, ws_us);
    hipLaunchKernelGGL(prep_featT, dim3(BB * HH), dim3(256), 0, stream, feat, featT);
    hipLaunchKernelGGL(liif_main, dim3((BB * QQ) / 32), dim3(256), 0, stream,
                       coord, cell, b0, b1, b2, b3, b4, ws_us, featT,
                       (float*)d_out);
}

// Round 6
// 478.957 us; speedup vs baseline: 1.2088x; 1.0187x over previous
//
#include <hip/hip_runtime.h>
#include <cstdint>

typedef __bf16 bf16x8 __attribute__((ext_vector_type(8)));
typedef float f32x4 __attribute__((ext_vector_type(4)));
typedef float f32x16 __attribute__((ext_vector_type(16)));
typedef unsigned int u32x4 __attribute__((ext_vector_type(4)));
typedef unsigned int u32x2 __attribute__((ext_vector_type(2)));
typedef unsigned short u16;
typedef unsigned int u32;

// Problem constants (fixed by reference)
#define HH 128
#define WW 128
#define CC 64
#define QQ 65536
#define BB 4

// LDS activation row stride in u16: 256 features + 8 pad.
#define RS 264

// Packed-weight offsets in bf16 elements inside d_ws.
#define L0_OFF 0        // 40 * 512 = 20480
#define L1_OFF 20480    // 128 * 512 = 65536
#define L2_OFF 86016
#define L3_OFF 151552
#define W4_OFF 217088   // 8 * 512 = 4096 -> total 221184 elems = 442368 B
#define FEATT_BYTE_OFF 524288u  // featT: 4*128*128*64 bf16 = 8388608 B

// Light barrier: LDS-ordering only.  __syncthreads() drains vmcnt(0) too,
// which would WAIT for the deliberately-in-flight weight preloads (the m97
// barrier-drain stall).  lgkmcnt(0)+s_barrier keeps the LDS hazard ordering
// (each wave drains its own ds ops; barrier makes it global) while global
// loads stay outstanding until their first VGPR use.
#define LBAR()                                            \
    do {                                                  \
        asm volatile("s_waitcnt lgkmcnt(0)" ::: "memory");\
        __builtin_amdgcn_s_barrier();                     \
        asm volatile("" ::: "memory");                    \
    } while (0)

// ---------------------------------------------------------------------------
// Pack w0..w3 into 32x32x16 MFMA fragment order (bf16):
//   frag (ks,nt): lane l, j=0..7 holds W[ks*16 + (l>>5)*8 + j][nt*32 + (l&31)]
// w4 (256->3) stays in 16x16x32 fragment order (kt-major, NT=1).
// ---------------------------------------------------------------------------
__global__ void pack_weights(const float* __restrict__ w0,
                             const float* __restrict__ w1,
                             const float* __restrict__ w2,
                             const float* __restrict__ w3,
                             const float* __restrict__ w4,
                             u16* __restrict__ ws_us) {
    int bid = blockIdx.x;
    int lane = threadIdx.x;  // 64
    int dst, kbase, n, Ksrc, Ncols;
    const float* w;
    if (bid < 424) {  // 32x32x16 fragments for L0..L3
        int tile, off;
        if (bid < 40)       { tile = bid;       off = L0_OFF; w = w0; Ksrc = 68;  }
        else if (bid < 168) { tile = bid - 40;  off = L1_OFF; w = w1; Ksrc = 256; }
        else if (bid < 296) { tile = bid - 168; off = L2_OFF; w = w2; Ksrc = 256; }
        else                { tile = bid - 296; off = L3_OFF; w = w3; Ksrc = 256; }
        int nt = tile & 7, ks = tile >> 3;
        n = nt * 32 + (lane & 31);
        kbase = ks * 16 + (lane >> 5) * 8;
        Ncols = 256;
        dst = off + tile * 512 + lane * 8;
    } else {          // w4: 16x16x32 fragments, frag kt = bid-424
        int kt = bid - 424;
        n = lane & 15;
        kbase = kt * 32 + (lane >> 4) * 8;
        w = w4; Ksrc = 256; Ncols = 3;
        dst = W4_OFF + kt * 512 + lane * 8;
    }
    unsigned int d[4];
    for (int i = 0; i < 4; ++i) {
        unsigned int lo, hi;
        {
            int k = kbase + 2 * i;
            float x = (k < Ksrc && n < Ncols) ? w[k * Ncols + n] : 0.0f;
            __bf16 hb = (__bf16)x;
            lo = (unsigned int)__builtin_bit_cast(u16, hb);
        }
        {
            int k = kbase + 2 * i + 1;
            float x = (k < Ksrc && n < Ncols) ? w[k * Ncols + n] : 0.0f;
            __bf16 hb = (__bf16)x;
            hi = (unsigned int)__builtin_bit_cast(u16, hb);
        }
        d[i] = lo | (hi << 16);
    }
    u32x4 pk = { d[0], d[1], d[2], d[3] };
    *reinterpret_cast<u32x4*>(ws_us + dst) = pk;
}

// ---------------------------------------------------------------------------
// feat [B,C,H,W] fp32 -> featT [B,H,W,C] bf16 (per-pixel gather = one
// contiguous 128B read). One block per (b, y) row; LDS transpose.
// ---------------------------------------------------------------------------
__global__ void prep_featT(const float* __restrict__ feat, u16* __restrict__ featT) {
    __shared__ u16 tile[128 * 66];
    int bid = blockIdx.x;
    int b = bid >> 7, y = bid & 127;
    for (int idx = threadIdx.x; idx < CC * WW; idx += 256) {
        int c = idx >> 7, x = idx & 127;
        float v = feat[(((b * CC + c) * HH + y) * WW) + x];
        __bf16 hb = (__bf16)v;
        tile[x * 66 + c] = __builtin_bit_cast(u16, hb);
    }
    __syncthreads();
    for (int idx = threadIdx.x; idx < 2048; idx += 256) {
        int x = idx >> 4, c4 = (idx & 15) * 4;
        const u16* src = tile + x * 66 + c4;
        u32x2 d;
        d[0] = (unsigned int)src[0] | ((unsigned int)src[1] << 16);
        d[1] = (unsigned int)src[2] | ((unsigned int)src[3] << 16);
        *reinterpret_cast<u32x2*>(featT + ((b * HH + y) * WW + x) * CC + c4) = d;
    }
}

// ---------------------------------------------------------------------------
// Preload the first THREE ksteps' fragments (6 x 16B) of a layer; issued
// BEFORE the (light) barrier so L2 latency genuinely overlaps the barrier +
// epilogue (vmcnt NOT drained by LBAR).
// ---------------------------------------------------------------------------
__device__ __forceinline__ void preload6(u32x4 w[6], const u32x4* __restrict__ b,
                                         int v, int kstr) {
    w[0] = b[v];
    w[1] = b[v + 64];
    w[2] = b[v + kstr];
    w[3] = b[v + kstr + 64];
    w[4] = b[v + 2 * kstr];
    w[5] = b[v + 2 * kstr + 64];
}

// ---------------------------------------------------------------------------
// Transposed GEMM layer via 32x32x16 MFMA, IN-PLACE: Y^T = W^T[256,K]*X^T[K,128].
// 128 samples/block.  Wave = 2 nt x 4 st.  Weight ring wq[3][2]; X ring
// xc[2][4].  Epilogue: bias add + relu + v_cvt_pk_bf16_f32 + ds_write_b64.
// C layout (verified): sample col = lane&31, feature row =
// (reg&3) + 8*(reg>>2) + 4*(lane>>5).
// ---------------------------------------------------------------------------
template <int NKS>
__device__ __forceinline__ void gemm32(u16* buf,
                                       const u32x4* __restrict__ wbase,
                                       const float* __restrict__ bias,
                                       int wave, int lane,
                                       const u32x4 wpre[6],
                                       u32x4 wnxt[6],
                                       const u32x4* __restrict__ wnb,
                                       int vnxt, int nkstr) {
    f32x16 acc[2][4] = {};                        // [ft][st]
    const int l31 = lane & 31;
    const int hi = lane >> 5;
    const int voff = wave * 128 + lane;           // u32x4 index of frag(ks=0, nt=wave*2)
    const u16* xb = buf + l31 * RS + hi * 8;      // one LDS base for ALL reads
    u16* db = buf + l31 * RS + wave * 64 + hi * 4;

    u32x4 wq[3][2];
    wq[0][0] = wpre[0]; wq[0][1] = wpre[1];
    wq[1][0] = wpre[2]; wq[1][1] = wpre[3];
    wq[2][0] = wpre[4]; wq[2][1] = wpre[5];

    bf16x8 xc[2][4];                              // [ks&1][st]
#pragma unroll
    for (int st = 0; st < 4; ++st) {
        xc[0][st] = __builtin_bit_cast(bf16x8,
            *reinterpret_cast<const u32x4*>(xb + st * 32 * RS));
        xc[1][st] = __builtin_bit_cast(bf16x8,
            *reinterpret_cast<const u32x4*>(xb + st * 32 * RS + 16));
    }

#pragma unroll
    for (int ks = 0; ks < NKS; ++ks) {
        const int ws = ks % 3;
        const int xs = ks & 1;
#pragma unroll
        for (int st = 0; st < 4; ++st) {
            acc[0][st] = __builtin_amdgcn_mfma_f32_32x32x16_bf16(
                __builtin_bit_cast(bf16x8, wq[ws][0]), xc[xs][st], acc[0][st], 0, 0, 0);
            acc[1][st] = __builtin_amdgcn_mfma_f32_32x32x16_bf16(
                __builtin_bit_cast(bf16x8, wq[ws][1]), xc[xs][st], acc[1][st], 0, 0, 0);
            if (ks + 2 < NKS)
                xc[xs][st] = __builtin_bit_cast(bf16x8,
                    *reinterpret_cast<const u32x4*>(xb + st * 32 * RS + (ks + 2) * 16));
        }
        if (ks + 3 < NKS) {
            const u32x4* wn = wbase + (ks + 3) * 512;
            wq[ws][0] = wn[voff];
            wq[ws][1] = wn[voff + 64];
        }
    }

    // Next layer's first-three-kstep fragments: issued here, they stay in
    // flight across BOTH light barriers and are first waited at their MFMA
    // use next layer (hidden under xc-init LDS reads).
    wnxt[0] = wnb[vnxt];
    wnxt[1] = wnb[vnxt + 64];
    wnxt[2] = wnb[vnxt + nkstr];
    wnxt[3] = wnb[vnxt + nkstr + 64];
    wnxt[4] = wnb[vnxt + 2 * nkstr];
    wnxt[5] = wnb[vnxt + 2 * nkstr + 64];

    LBAR();  // all waves' ds_reads of buf complete -> in-place write OK

    // Epilogue: bias + relu + packed bf16 cvt + ds_write_b64, imm offsets.
#pragma unroll
    for (int ft = 0; ft < 2; ++ft) {
        const int fb = wave * 64 + ft * 32 + hi * 4;
#pragma unroll
        for (int q4 = 0; q4 < 4; ++q4) {
            f32x4 bv = *reinterpret_cast<const f32x4*>(bias + fb + q4 * 8);
#pragma unroll
            for (int st = 0; st < 4; ++st) {
                float v0 = fmaxf(acc[ft][st][q4 * 4 + 0] + bv[0], 0.0f);
                float v1 = fmaxf(acc[ft][st][q4 * 4 + 1] + bv[1], 0.0f);
                float v2 = fmaxf(acc[ft][st][q4 * 4 + 2] + bv[2], 0.0f);
                float v3 = fmaxf(acc[ft][st][q4 * 4 + 3] + bv[3], 0.0f);
                u32 lo, hi2;
                asm("v_cvt_pk_bf16_f32 %0, %1, %2" : "=v"(lo)  : "v"(v0), "v"(v1));
                asm("v_cvt_pk_bf16_f32 %0, %1, %2" : "=v"(hi2) : "v"(v2), "v"(v3));
                u32x2 d = { lo, hi2 };
                *reinterpret_cast<u32x2*>(db + st * 32 * RS + ft * 32 + q4 * 8) = d;
            }
        }
    }
}

// ---------------------------------------------------------------------------
// Main fused kernel: 32 queries x 4 branches = 128 rows (samples) per block.
// Single 67.6KB activation buffer (in-place layers) -> 2 blocks/CU.
// ---------------------------------------------------------------------------
__global__ __launch_bounds__(256, 2) void liif_main(
    const float* __restrict__ coord, const float* __restrict__ cell,
    const float* __restrict__ b0, const float* __restrict__ b1,
    const float* __restrict__ b2, const float* __restrict__ b3,
    const float* __restrict__ b4,
    const u16* __restrict__ wpack, const u16* __restrict__ featT,
    float* __restrict__ out) {
    __shared__ u16 bufA[128 * RS];   // 67584 B
    __shared__ float areasLDS[128];

    const int t = threadIdx.x;
    const int wave = t >> 6, lane = t & 63;
    const int row = t >> 1, p = t & 1;   // 128 rows, 2 threads per row

    // ---- stage X0 (branch math + feature gather), 2 threads per row ----
    const int bq = blockIdx.x * 32 + (row >> 2);
    const int v = row & 3;
    const int b = bq >> 16;  // Q = 65536
    const float c0 = coord[bq * 2 + 0];
    const float c1 = coord[bq * 2 + 1];
    const float rc0 = cell[bq * 2 + 0] * 128.0f;
    const float rc1 = cell[bq * 2 + 1] * 128.0f;
    const float eps = 1e-6f;
    const float sx = ((v & 2) ? 0.0078125f : -0.0078125f) + eps;
    const float sy = ((v & 1) ? 0.0078125f : -0.0078125f) + eps;
    float cs0 = fminf(fmaxf(c0 + sx, -1.0f + eps), 1.0f - eps);
    float cs1 = fminf(fmaxf(c1 + sy, -1.0f + eps), 1.0f - eps);
    float fy = fminf(fmaxf(floorf((cs0 + 1.0f) * 64.0f), 0.0f), 127.0f);
    float fx = fminf(fmaxf(floorf((cs1 + 1.0f) * 64.0f), 0.0f), 127.0f);
    int iy = (int)fy, ix = (int)fx;
    float qc0 = -1.0f + (2.0f * fy + 1.0f) * 0.0078125f;
    float qc1 = -1.0f + (2.0f * fx + 1.0f) * 0.0078125f;
    float rel0 = (c0 - qc0) * 128.0f;
    float rel1 = (c1 - qc1) * 128.0f;
    float area = fabsf(rel0 * rel1) + 1e-9f;

    {
        // 32 features per thread (4 x b128)
        const u16* fr = featT + (((b * HH + iy) * WW + ix) * CC) + p * 32;
        u32x4 f0 = *reinterpret_cast<const u32x4*>(fr);
        u32x4 f1 = *reinterpret_cast<const u32x4*>(fr + 8);
        u32x4 f2 = *reinterpret_cast<const u32x4*>(fr + 16);
        u32x4 f3 = *reinterpret_cast<const u32x4*>(fr + 24);
        u16* sb = bufA + row * RS;
        *reinterpret_cast<u32x4*>(sb + p * 32) = f0;
        *reinterpret_cast<u32x4*>(sb + p * 32 + 8) = f1;
        *reinterpret_cast<u32x4*>(sb + p * 32 + 16) = f2;
        *reinterpret_cast<u32x4*>(sb + p * 32 + 24) = f3;
        u32x4 e = { 0u, 0u, 0u, 0u };
        u32x4 z = { 0u, 0u, 0u, 0u };
        if (p == 0) {
            __bf16 h0 = (__bf16)rel0, h1 = (__bf16)rel1, h2 = (__bf16)rc0, h3 = (__bf16)rc1;
            e[0] = (u32)__builtin_bit_cast(u16, h0) | ((u32)__builtin_bit_cast(u16, h1) << 16);
            e[1] = (u32)__builtin_bit_cast(u16, h2) | ((u32)__builtin_bit_cast(u16, h3) << 16);
            areasLDS[row] = area;
        }
        // features 64..95 (reals in first 4 of p==0's chunk, zeros elsewhere)
        *reinterpret_cast<u32x4*>(sb + 64 + p * 16) = e;
        *reinterpret_cast<u32x4*>(sb + 64 + p * 16 + 8) = z;
    }

    const u32x4* wp = reinterpret_cast<const u32x4*>(wpack);
    const u32x4* wp0 = wp + (L0_OFF / 8);
    const u32x4* wp1 = wp + (L1_OFF / 8);
    const u32x4* wp2 = wp + (L2_OFF / 8);
    const u32x4* wp3 = wp + (L3_OFF / 8);
    const u32x4* wp4 = wp + (W4_OFF / 8);
    const int voff = wave * 128 + lane;  // frag(ks=0, nt=wave*2) for 32x32 layers

    u32x4 wA[6], wB[6];
    preload6(wA, wp0, voff, 512);
    LBAR();
    gemm32<5>(bufA, wp0, b0, wave, lane, wA, wB, wp1, voff, 512);
    LBAR();
    gemm32<16>(bufA, wp1, b1, wave, lane, wB, wA, wp2, voff, 512);
    LBAR();
    gemm32<16>(bufA, wp2, b2, wave, lane, wA, wB, wp3, voff, 512);
    LBAR();
    // wnb = wp4 with vnxt = lane, nkstr = 128: wB <- w4 frags kt = 0..5
    // (16x16 layout, frag kt at u32x4 offset kt*64).
    gemm32<16>(bufA, wp3, b3, wave, lane, wB, wA, wp4, lane, 128);
    // w4 kt=6,7 fragments
    u32x4 w4hi[2];
#pragma unroll
    for (int kt = 0; kt < 2; ++kt) w4hi[kt] = wp4[(kt + 6) * 64 + lane];
    LBAR();

    // ---- final layer 256->3 via 16x16x32 MFMA; wave handles 2 st tiles ----
    const int l15 = lane & 15;
    const int qd = lane >> 4;
    const u16* xb4 = bufA + (wave * 32 + l15) * RS + qd * 8;
    f32x4 accf[2] = {};
#pragma unroll
    for (int kt = 0; kt < 8; ++kt) {
        bf16x8 a = __builtin_bit_cast(bf16x8, (kt < 6) ? wA[kt] : w4hi[kt - 6]);
        bf16x8 x0 = __builtin_bit_cast(bf16x8,
            *reinterpret_cast<const u32x4*>(xb4 + kt * 32));
        accf[0] = __builtin_amdgcn_mfma_f32_16x16x32_bf16(a, x0, accf[0], 0, 0, 0);
        bf16x8 x1 = __builtin_bit_cast(bf16x8,
            *reinterpret_cast<const u32x4*>(xb4 + 16 * RS + kt * 32));
        accf[1] = __builtin_amdgcn_mfma_f32_16x16x32_bf16(a, x1, accf[1], 0, 0, 0);
    }
    // lane (qd==0) holds pred[0..2] for samples wave*32 + stl*16 + l15.
#pragma unroll
    for (int stl = 0; stl < 2; ++stl) {
        float a = areasLDS[wave * 32 + stl * 16 + l15];
        float a1 = a + __shfl_xor(a, 1);
        float asum = a1 + __shfl_xor(a1, 2);
        float aopp = __shfl_xor(a, 3);  // diagonal swap 0<->3, 1<->2
        float wgt = aopp / asum;
        float o0 = (accf[stl][0] + b4[0]) * wgt;
        float o1 = (accf[stl][1] + b4[1]) * wgt;
        float o2 = (accf[stl][2] + b4[2]) * wgt;
        o0 += __shfl_xor(o0, 1); o0 += __shfl_xor(o0, 2);
        o1 += __shfl_xor(o1, 1); o1 += __shfl_xor(o1, 2);
        o2 += __shfl_xor(o2, 1); o2 += __shfl_xor(o2, 2);
        if (qd == 0 && (l15 & 3) == 0) {
            int obq = blockIdx.x * 32 + wave * 8 + stl * 4 + (l15 >> 2);
            out[obq * 3 + 0] = o0;
            out[obq * 3 + 1] = o1;
            out[obq * 3 + 2] = o2;
        }
    }
}

// ---------------------------------------------------------------------------
extern "C" void kernel_launch(void* const* d_in, const int* in_sizes, int n_in,
                              void* d_out, int out_size, void* d_ws, size_t ws_size,
                              hipStream_t stream) {
    const float* feat  = (const float*)d_in[0];
    const float* coord = (const float*)d_in[1];
    const float* cell  = (const float*)d_in[2];
    const float* w0 = (const float*)d_in[3];
    const float* b0 = (const float*)d_in[4];
    const float* w1 = (const float*)d_in[5];
    const float* b1 = (const float*)d_in[6];
    const float* w2 = (const float*)d_in[7];
    const float* b2 = (const float*)d_in[8];
    const float* w3 = (const float*)d_in[9];
    const float* b3 = (const float*)d_in[10];
    const float* w4 = (const float*)d_in[11];
    const float* b4 = (const float*)d_in[12];

    u16* ws_us = (u16*)d_ws;
    u16* featT = (u16*)((char*)d_ws + FEATT_BYTE_OFF);
    // ws need: 524288 + 8388608 = 8912896 bytes

    hipLaunchKernelGGL(pack_weights, dim3(432), dim3(64), 0, stream,
                       w0, w1, w2, w3, w4, ws_us);
    hipLaunchKernelGGL(prep_featT, dim3(BB * HH), dim3(256), 0, stream, feat, featT);
    hipLaunchKernelGGL(liif_main, dim3((BB * QQ) / 32), dim3(256), 0, stream,
                       coord, cell, b0, b1, b2, b3, b4, ws_us, featT,
                       (float*)d_out);
}

// Round 7
// 466.529 us; speedup vs baseline: 1.2410x; 1.0266x over previous
//
#include <hip/hip_runtime.h>
#include <cstdint>

typedef __bf16 bf16x8 __attribute__((ext_vector_type(8)));
typedef float f32x4 __attribute__((ext_vector_type(4)));
typedef float f32x16 __attribute__((ext_vector_type(16)));
typedef unsigned int u32x4 __attribute__((ext_vector_type(4)));
typedef unsigned int u32x2 __attribute__((ext_vector_type(2)));
typedef unsigned short u16;
typedef unsigned int u32;

// Problem constants (fixed by reference)
#define HH 128
#define WW 128
#define CC 64
#define QQ 65536
#define BB 4

// Samples per block: 96 (24 queries x 4 branches) -> LDS 51.1KB -> 3 blocks/CU.
#define SAMP 96
#define QPB 24

// LDS activation row stride in u16: 256 features + 8 pad.
#define RS 264

// Packed-weight offsets in bf16 elements inside d_ws.
#define L0_OFF 0        // 40 * 512 = 20480
#define L1_OFF 20480    // 128 * 512 = 65536
#define L2_OFF 86016
#define L3_OFF 151552
#define W4_OFF 217088   // 8 * 512 = 4096 -> total 221184 elems = 442368 B
#define FEATT_BYTE_OFF 524288u  // featT: 4*128*128*64 bf16 = 8388608 B

// Light barrier: LDS-ordering only (lgkmcnt), vmcnt stays in flight.
#define LBAR()                                            \
    do {                                                  \
        asm volatile("s_waitcnt lgkmcnt(0)" ::: "memory");\
        __builtin_amdgcn_s_barrier();                     \
        asm volatile("" ::: "memory");                    \
    } while (0)

// ---------------------------------------------------------------------------
// Pack w0..w3 into 32x32x16 MFMA fragment order (bf16):
//   frag (ks,nt): lane l, j=0..7 holds W[ks*16 + (l>>5)*8 + j][nt*32 + (l&31)]
// w4 (256->3) stays in 16x16x32 fragment order (kt-major, NT=1).
// ---------------------------------------------------------------------------
__global__ void pack_weights(const float* __restrict__ w0,
                             const float* __restrict__ w1,
                             const float* __restrict__ w2,
                             const float* __restrict__ w3,
                             const float* __restrict__ w4,
                             u16* __restrict__ ws_us) {
    int bid = blockIdx.x;
    int lane = threadIdx.x;  // 64
    int dst, kbase, n, Ksrc, Ncols;
    const float* w;
    if (bid < 424) {  // 32x32x16 fragments for L0..L3
        int tile, off;
        if (bid < 40)       { tile = bid;       off = L0_OFF; w = w0; Ksrc = 68;  }
        else if (bid < 168) { tile = bid - 40;  off = L1_OFF; w = w1; Ksrc = 256; }
        else if (bid < 296) { tile = bid - 168; off = L2_OFF; w = w2; Ksrc = 256; }
        else                { tile = bid - 296; off = L3_OFF; w = w3; Ksrc = 256; }
        int nt = tile & 7, ks = tile >> 3;
        n = nt * 32 + (lane & 31);
        kbase = ks * 16 + (lane >> 5) * 8;
        Ncols = 256;
        dst = off + tile * 512 + lane * 8;
    } else {          // w4: 16x16x32 fragments, frag kt = bid-424
        int kt = bid - 424;
        n = lane & 15;
        kbase = kt * 32 + (lane >> 4) * 8;
        w = w4; Ksrc = 256; Ncols = 3;
        dst = W4_OFF + kt * 512 + lane * 8;
    }
    unsigned int d[4];
    for (int i = 0; i < 4; ++i) {
        unsigned int lo, hi;
        {
            int k = kbase + 2 * i;
            float x = (k < Ksrc && n < Ncols) ? w[k * Ncols + n] : 0.0f;
            __bf16 hb = (__bf16)x;
            lo = (unsigned int)__builtin_bit_cast(u16, hb);
        }
        {
            int k = kbase + 2 * i + 1;
            float x = (k < Ksrc && n < Ncols) ? w[k * Ncols + n] : 0.0f;
            __bf16 hb = (__bf16)x;
            hi = (unsigned int)__builtin_bit_cast(u16, hb);
        }
        d[i] = lo | (hi << 16);
    }
    u32x4 pk = { d[0], d[1], d[2], d[3] };
    *reinterpret_cast<u32x4*>(ws_us + dst) = pk;
}

// ---------------------------------------------------------------------------
// feat [B,C,H,W] fp32 -> featT [B,H,W,C] bf16.
// ---------------------------------------------------------------------------
__global__ void prep_featT(const float* __restrict__ feat, u16* __restrict__ featT) {
    __shared__ u16 tile[128 * 66];
    int bid = blockIdx.x;
    int b = bid >> 7, y = bid & 127;
    for (int idx = threadIdx.x; idx < CC * WW; idx += 256) {
        int c = idx >> 7, x = idx & 127;
        float v = feat[(((b * CC + c) * HH + y) * WW) + x];
        __bf16 hb = (__bf16)v;
        tile[x * 66 + c] = __builtin_bit_cast(u16, hb);
    }
    __syncthreads();
    for (int idx = threadIdx.x; idx < 2048; idx += 256) {
        int x = idx >> 4, c4 = (idx & 15) * 4;
        const u16* src = tile + x * 66 + c4;
        u32x2 d;
        d[0] = (unsigned int)src[0] | ((unsigned int)src[1] << 16);
        d[1] = (unsigned int)src[2] | ((unsigned int)src[3] << 16);
        *reinterpret_cast<u32x2*>(featT + ((b * HH + y) * WW + x) * CC + c4) = d;
    }
}

// ---------------------------------------------------------------------------
// Transposed GEMM layer, 32x32x16 MFMA, IN-PLACE: Y^T = W^T[256,K]*X^T[K,96].
// Wave = 2 nt x 3 st (64 features x 96 samples).  acc = 96 AGPR; weight ring
// wq[3][2] loaded AT LAYER ENTRY (no cross-layer preload: saves 48 VGPR so
// 3 blocks/CU fit; entry L2 latency covered by xc/acc init + 3rd wave TLP).
// C layout (verified): sample col = lane&31, feature row =
// (reg&3) + 8*(reg>>2) + 4*(lane>>5).
// ---------------------------------------------------------------------------
template <int NKS>
__device__ __forceinline__ void gemm32(u16* buf,
                                       const u32x4* __restrict__ wbase,
                                       const float* __restrict__ bias,
                                       int wave, int lane) {
    f32x16 acc[2][3] = {};                        // [ft][st]
    const int l31 = lane & 31;
    const int hi = lane >> 5;
    const int voff = wave * 128 + lane;           // u32x4 index of frag(ks=0, nt=wave*2)
    const u16* xb = buf + l31 * RS + hi * 8;      // one LDS base for ALL reads
    u16* db = buf + l31 * RS + wave * 64 + hi * 4;

    u32x4 wq[3][2];
#pragma unroll
    for (int i = 0; i < 3; ++i) {
        wq[i][0] = wbase[i * 512 + voff];
        wq[i][1] = wbase[i * 512 + voff + 64];
    }

    bf16x8 xc[2][3];                              // [ks&1][st]
#pragma unroll
    for (int st = 0; st < 3; ++st) {
        xc[0][st] = __builtin_bit_cast(bf16x8,
            *reinterpret_cast<const u32x4*>(xb + st * 32 * RS));
        xc[1][st] = __builtin_bit_cast(bf16x8,
            *reinterpret_cast<const u32x4*>(xb + st * 32 * RS + 16));
    }

#pragma unroll
    for (int ks = 0; ks < NKS; ++ks) {
        const int ws = ks % 3;
        const int xs = ks & 1;
#pragma unroll
        for (int st = 0; st < 3; ++st) {
            acc[0][st] = __builtin_amdgcn_mfma_f32_32x32x16_bf16(
                __builtin_bit_cast(bf16x8, wq[ws][0]), xc[xs][st], acc[0][st], 0, 0, 0);
            acc[1][st] = __builtin_amdgcn_mfma_f32_32x32x16_bf16(
                __builtin_bit_cast(bf16x8, wq[ws][1]), xc[xs][st], acc[1][st], 0, 0, 0);
            if (ks + 2 < NKS)
                xc[xs][st] = __builtin_bit_cast(bf16x8,
                    *reinterpret_cast<const u32x4*>(xb + st * 32 * RS + (ks + 2) * 16));
        }
        if (ks + 3 < NKS) {
            const u32x4* wn = wbase + (ks + 3) * 512;
            wq[ws][0] = wn[voff];
            wq[ws][1] = wn[voff + 64];
        }
    }

    LBAR();  // all waves' ds_reads of buf complete -> in-place write OK

    // Epilogue: bias + relu + packed bf16 cvt + ds_write_b64, imm offsets.
#pragma unroll
    for (int ft = 0; ft < 2; ++ft) {
        const int fb = wave * 64 + ft * 32 + hi * 4;
#pragma unroll
        for (int q4 = 0; q4 < 4; ++q4) {
            f32x4 bv = *reinterpret_cast<const f32x4*>(bias + fb + q4 * 8);
#pragma unroll
            for (int st = 0; st < 3; ++st) {
                float v0 = fmaxf(acc[ft][st][q4 * 4 + 0] + bv[0], 0.0f);
                float v1 = fmaxf(acc[ft][st][q4 * 4 + 1] + bv[1], 0.0f);
                float v2 = fmaxf(acc[ft][st][q4 * 4 + 2] + bv[2], 0.0f);
                float v3 = fmaxf(acc[ft][st][q4 * 4 + 3] + bv[3], 0.0f);
                u32 lo, hi2;
                asm("v_cvt_pk_bf16_f32 %0, %1, %2" : "=v"(lo)  : "v"(v0), "v"(v1));
                asm("v_cvt_pk_bf16_f32 %0, %1, %2" : "=v"(hi2) : "v"(v2), "v"(v3));
                u32x2 d = { lo, hi2 };
                *reinterpret_cast<u32x2*>(db + st * 32 * RS + ft * 32 + q4 * 8) = d;
            }
        }
    }
}

// ---------------------------------------------------------------------------
// Main fused kernel: 24 queries x 4 branches = 96 rows (samples) per block.
// 51.1KB LDS + <=170 unified regs -> 3 blocks/CU (12 waves/CU).
// ---------------------------------------------------------------------------
__global__ __launch_bounds__(256, 3) void liif_main(
    const float* __restrict__ coord, const float* __restrict__ cell,
    const float* __restrict__ b0, const float* __restrict__ b1,
    const float* __restrict__ b2, const float* __restrict__ b3,
    const float* __restrict__ b4,
    const u16* __restrict__ wpack, const u16* __restrict__ featT,
    float* __restrict__ out) {
    __shared__ u16 bufA[SAMP * RS];   // 50688 B
    __shared__ float areasLDS[SAMP];

    const int t = threadIdx.x;
    const int wave = t >> 6, lane = t & 63;

    // ---- stage X0 (branch math + feature gather): 2 threads per row,
    //      threads 0..191 cover rows 0..95; wave 3 idles here ----
    if (t < 2 * SAMP) {
        const int row = t >> 1, p = t & 1;
        int bq = blockIdx.x * QPB + (row >> 2);
        if (bq > BB * QQ - 1) bq = BB * QQ - 1;   // tail-block clamp (writes guarded later)
        const int v = row & 3;
        const int b = bq >> 16;  // Q = 65536
        const float c0 = coord[bq * 2 + 0];
        const float c1 = coord[bq * 2 + 1];
        const float rc0 = cell[bq * 2 + 0] * 128.0f;
        const float rc1 = cell[bq * 2 + 1] * 128.0f;
        const float eps = 1e-6f;
        const float sx = ((v & 2) ? 0.0078125f : -0.0078125f) + eps;
        const float sy = ((v & 1) ? 0.0078125f : -0.0078125f) + eps;
        float cs0 = fminf(fmaxf(c0 + sx, -1.0f + eps), 1.0f - eps);
        float cs1 = fminf(fmaxf(c1 + sy, -1.0f + eps), 1.0f - eps);
        float fy = fminf(fmaxf(floorf((cs0 + 1.0f) * 64.0f), 0.0f), 127.0f);
        float fx = fminf(fmaxf(floorf((cs1 + 1.0f) * 64.0f), 0.0f), 127.0f);
        int iy = (int)fy, ix = (int)fx;
        float qc0 = -1.0f + (2.0f * fy + 1.0f) * 0.0078125f;
        float qc1 = -1.0f + (2.0f * fx + 1.0f) * 0.0078125f;
        float rel0 = (c0 - qc0) * 128.0f;
        float rel1 = (c1 - qc1) * 128.0f;
        float area = fabsf(rel0 * rel1) + 1e-9f;

        // 32 features per thread (4 x b128)
        const u16* fr = featT + (((b * HH + iy) * WW + ix) * CC) + p * 32;
        u32x4 f0 = *reinterpret_cast<const u32x4*>(fr);
        u32x4 f1 = *reinterpret_cast<const u32x4*>(fr + 8);
        u32x4 f2 = *reinterpret_cast<const u32x4*>(fr + 16);
        u32x4 f3 = *reinterpret_cast<const u32x4*>(fr + 24);
        u16* sb = bufA + row * RS;
        *reinterpret_cast<u32x4*>(sb + p * 32) = f0;
        *reinterpret_cast<u32x4*>(sb + p * 32 + 8) = f1;
        *reinterpret_cast<u32x4*>(sb + p * 32 + 16) = f2;
        *reinterpret_cast<u32x4*>(sb + p * 32 + 24) = f3;
        u32x4 e = { 0u, 0u, 0u, 0u };
        u32x4 z = { 0u, 0u, 0u, 0u };
        if (p == 0) {
            __bf16 h0 = (__bf16)rel0, h1 = (__bf16)rel1, h2 = (__bf16)rc0, h3 = (__bf16)rc1;
            e[0] = (u32)__builtin_bit_cast(u16, h0) | ((u32)__builtin_bit_cast(u16, h1) << 16);
            e[1] = (u32)__builtin_bit_cast(u16, h2) | ((u32)__builtin_bit_cast(u16, h3) << 16);
            areasLDS[row] = area;
        }
        // features 64..95 (reals in first 4 of p==0's chunk, zeros elsewhere)
        *reinterpret_cast<u32x4*>(sb + 64 + p * 16) = e;
        *reinterpret_cast<u32x4*>(sb + 64 + p * 16 + 8) = z;
    }

    const u32x4* wp = reinterpret_cast<const u32x4*>(wpack);
    const u32x4* wp0 = wp + (L0_OFF / 8);
    const u32x4* wp1 = wp + (L1_OFF / 8);
    const u32x4* wp2 = wp + (L2_OFF / 8);
    const u32x4* wp3 = wp + (L3_OFF / 8);
    const u32x4* wp4 = wp + (W4_OFF / 8);

    LBAR();
    gemm32<5>(bufA, wp0, b0, wave, lane);
    LBAR();
    gemm32<16>(bufA, wp1, b1, wave, lane);
    LBAR();
    gemm32<16>(bufA, wp2, b2, wave, lane);
    LBAR();
    gemm32<16>(bufA, wp3, b3, wave, lane);
    // w4 fragments (16x16 layout, frag kt at u32x4 offset kt*64): issued
    // before the light barrier, in flight across it, first waited at MFMA use.
    u32x4 w4f[8];
#pragma unroll
    for (int kt = 0; kt < 8; ++kt) w4f[kt] = wp4[kt * 64 + lane];
    LBAR();

    // ---- final layer 256->3 via 16x16x32 MFMA over 6 sample tiles of 16:
    //      wave0:{0,4} wave1:{1,5} wave2:{2} wave3:{3} ----
    const int l15 = lane & 15;
    const int qd = lane >> 4;
    const int ntile = (wave < 2) ? 2 : 1;
    for (int stl = 0; stl < ntile; ++stl) {
        const int tile = wave + stl * 4;
        const u16* xb4 = bufA + (tile * 16 + l15) * RS + qd * 8;
        f32x4 accf = {};
#pragma unroll
        for (int kt = 0; kt < 8; ++kt) {
            bf16x8 x = __builtin_bit_cast(bf16x8,
                *reinterpret_cast<const u32x4*>(xb4 + kt * 32));
            accf = __builtin_amdgcn_mfma_f32_16x16x32_bf16(
                __builtin_bit_cast(bf16x8, w4f[kt]), x, accf, 0, 0, 0);
        }
        // lane (qd==0) holds pred[0..2] for sample = tile*16 + l15.
        float a = areasLDS[tile * 16 + l15];
        float a1 = a + __shfl_xor(a, 1);
        float asum = a1 + __shfl_xor(a1, 2);
        float aopp = __shfl_xor(a, 3);  // diagonal swap 0<->3, 1<->2
        float wgt = aopp / asum;
        float o0 = (accf[0] + b4[0]) * wgt;
        float o1 = (accf[1] + b4[1]) * wgt;
        float o2 = (accf[2] + b4[2]) * wgt;
        o0 += __shfl_xor(o0, 1); o0 += __shfl_xor(o0, 2);
        o1 += __shfl_xor(o1, 1); o1 += __shfl_xor(o1, 2);
        o2 += __shfl_xor(o2, 1); o2 += __shfl_xor(o2, 2);
        if (qd == 0 && (l15 & 3) == 0) {
            int obq = blockIdx.x * QPB + ((tile * 16 + l15) >> 2);
            if (obq < BB * QQ) {
                out[obq * 3 + 0] = o0;
                out[obq * 3 + 1] = o1;
                out[obq * 3 + 2] = o2;
            }
        }
    }
}

// ---------------------------------------------------------------------------
extern "C" void kernel_launch(void* const* d_in, const int* in_sizes, int n_in,
                              void* d_out, int out_size, void* d_ws, size_t ws_size,
                              hipStream_t stream) {
    const float* feat  = (const float*)d_in[0];
    const float* coord = (const float*)d_in[1];
    const float* cell  = (const float*)d_in[2];
    const float* w0 = (const float*)d_in[3];
    const float* b0 = (const float*)d_in[4];
    const float* w1 = (const float*)d_in[5];
    const float* b1 = (const float*)d_in[6];
    const float* w2 = (const float*)d_in[7];
    const float* b2 = (const float*)d_in[8];
    const float* w3 = (const float*)d_in[9];
    const float* b3 = (const float*)d_in[10];
    const float* w4 = (const float*)d_in[11];
    const float* b4 = (const float*)d_in[12];

    u16* ws_us = (u16*)d_ws;
    u16* featT = (u16*)((char*)d_ws + FEATT_BYTE_OFF);
    // ws need: 524288 + 8388608 = 8912896 bytes

    hipLaunchKernelGGL(pack_weights, dim3(432), dim3(64), 0, stream,
                       w0, w1, w2, w3, w4, ws_us);
    hipLaunchKernelGGL(prep_featT, dim3(BB * HH), dim3(256), 0, stream, feat, featT);
    hipLaunchKernelGGL(liif_main, dim3((BB * QQ + QPB - 1) / QPB), dim3(256), 0, stream,
                       coord, cell, b0, b1, b2, b3, b4, ws_us, featT,
                       (float*)d_out);
}